// Round 6
// baseline (14731.277 us; speedup 1.0000x reference)
//
#include <hip/hip_runtime.h>
#include <math.h>

#define PITCH 72      // old layout (small kernels only)
#define NP 68         // new pitch: word(row r, col c) = 68r+c ; bank = (4r+c) mod 32
#define SW_BATCH 12
#define SW_SMALL 10
#define NPART 32
#define EPS2_ROT 1e-12f   // (1e-6)^2 : threshold compared on d^2

// R4 post-mortem: the 1-pass register Jacobi needs ~150 live VGPRs; the
// allocator refused 3 rounds in a row (squeeze->spill/remat). New structure
// needs only ~90 live by design. Attr: min 2 waves/EU (budget 256 >> 90, no
// squeeze), max 8 (lets LDS set the cap: 4 blocks/CU for k1-k3 -> 16 waves/CU;
// R4's (1,2) attr was self-capping occupancy at 2 blocks/CU).
#define KATTR __attribute__((amdgpu_flat_work_group_size(256, 256), amdgpu_waves_per_eu(2, 8)))

// ---- workspace float-offsets ----
#define OFF_ACCG 0
#define OFF_ACCT (NPART*4096)
#define OFF_BASE (2*NPART*4096)
#define SL_MNH  (OFF_BASE + 0*4096)
#define SL_MH   (OFF_BASE + 1*4096)
#define SL_WH   (OFF_BASE + 2*4096)
#define SL_P    (OFF_BASE + 3*4096)
#define SL_Q    (OFF_BASE + 4*4096)
#define SL_GH   (OFF_BASE + 5*4096)
#define SL_GNH  (OFF_BASE + 6*4096)
#define SL_MNH2 (OFF_BASE + 7*4096)
#define SL_WCH  (OFF_BASE + 8*4096)
#define OFF_VAR (OFF_BASE + 9*4096)
#define SL_SC   (OFF_BASE + 9*4096 + 1)

struct __align__(16) F4 { float v[4]; };

// ======================================================================
// OLD infrastructure (PITCH 72) — used only by the 1-block small kernels
// ======================================================================
struct __align__(16) Smem {
  float S0[64*PITCH];
  float S1[64*PITCH];
  float w2[64];
  float wc[64];
  float red[256];
};

__device__ __forceinline__ void g2s(float* dst, const float* __restrict__ src) {
  int t = threadIdx.x;
#pragma unroll
  for (int i = 0; i < 4; ++i) {
    int e4 = t + (i << 8);
    F4 vv = *(const F4*)&src[e4 * 4];
    *(F4*)&dst[(e4 >> 4) * PITCH + (e4 & 15) * 4] = vv;
  }
  __syncthreads();
}
__device__ __forceinline__ void s2g(float* __restrict__ dst, const float* src) {
  int t = threadIdx.x;
#pragma unroll
  for (int i = 0; i < 4; ++i) {
    int e4 = t + (i << 8);
    F4 vv = *(const F4*)&src[(e4 >> 4) * PITCH + (e4 & 15) * 4];
    *(F4*)&dst[e4 * 4] = vv;
  }
  __syncthreads();
}

template<int MODE>   // 0: S0<-S1*S0 ; 1: S0<-S0*S1
__device__ void mmX(Smem& sm) {
  int t = threadIdx.x;
  int R0 = t >> 4;
  int J = (t & 15) * 4;
  float acc[4][4] = {};
  for (int kb = 0; kb < 64; kb += 4) {
    F4 a4[4], b4[4];
#pragma unroll
    for (int i = 0; i < 4; ++i) {
      const float* L = (MODE == 0) ? sm.S1 : sm.S0;
      a4[i] = *(const F4*)&L[(R0 + 16 * i) * PITCH + kb];
    }
#pragma unroll
    for (int kk = 0; kk < 4; ++kk) {
      const float* Rp = (MODE == 0) ? sm.S0 : sm.S1;
      b4[kk] = *(const F4*)&Rp[(kb + kk) * PITCH + J];
    }
#pragma unroll
    for (int i = 0; i < 4; ++i)
#pragma unroll
      for (int kk = 0; kk < 4; ++kk)
#pragma unroll
        for (int m = 0; m < 4; ++m)
          acc[i][m] = fmaf(a4[i].v[kk], b4[kk].v[m], acc[i][m]);
  }
  __syncthreads();
#pragma unroll
  for (int i = 0; i < 4; ++i) {
    F4 o;
#pragma unroll
    for (int m = 0; m < 4; ++m) o.v[m] = acc[i][m];
    *(F4*)&sm.S0[(R0 + 16 * i) * PITCH + J] = o;
  }
  __syncthreads();
}

__device__ void reconT(Smem& sm) {
  __syncthreads();
  int t = threadIdx.x;
  int R0 = t >> 4;
  int J = (t & 15) * 4;
  float acc[4][4] = {};
  for (int k = 0; k < 64; ++k) {
    float w = sm.wc[k];
    float a[4];
#pragma unroll
    for (int i = 0; i < 4; ++i) a[i] = w * sm.S0[k * PITCH + R0 + 16 * i];
    F4 b = *(const F4*)&sm.S0[k * PITCH + J];
#pragma unroll
    for (int i = 0; i < 4; ++i)
#pragma unroll
      for (int m = 0; m < 4; ++m) acc[i][m] = fmaf(a[i], b.v[m], acc[i][m]);
  }
#pragma unroll
  for (int i = 0; i < 4; ++i) {
    F4 o;
#pragma unroll
    for (int m = 0; m < 4; ++m) o.v[m] = acc[i][m];
    *(F4*)&sm.S1[(R0 + 16 * i) * PITCH + J] = o;
  }
  __syncthreads();
}

__device__ float frob2(Smem& sm) {
  int t = threadIdx.x;
  float s = 0.f;
#pragma unroll
  for (int i = 0; i < 4; ++i) {
    int e4 = t + (i << 8);
    F4 vv = *(const F4*)&sm.S0[(e4 >> 4) * PITCH + (e4 & 15) * 4];
#pragma unroll
    for (int m = 0; m < 4; ++m) s = fmaf(vv.v[m], vv.v[m], s);
  }
  sm.red[t] = s;
  __syncthreads();
  for (int o = 128; o; o >>= 1) { if (t < o) sm.red[t] += sm.red[t + o]; __syncthreads(); }
  float f = sm.red[0];
  __syncthreads();
  return f;
}

// ---------- register-resident wave-synchronous one-sided Jacobi ----------
// lane l holds column l (= row l of the symmetric input) in own[64].
// XOR ordering: round m pairs lane l with lane l^m (m=1..63). Both lanes
// compute bitwise-identical d (products commute, same summation order).
// EXPLICIT 2-PASS structure, peak liveness ~own[64]+8 (≈90 VGPR) by design:
//   pass 1: chunked shfl -> dot (pv dies per 8-chunk)
//   pass 2: only if rotating, chunked shfl -> rotate (pv dies per 8-chunk)
// The empty asm "+v" fence between passes breaks value-identity of own[] so
// the compiler cannot CSE pass-2 shuffles with pass-1 (which would resurrect
// a 64-live pv array -> R2/R3/R4's spill/remat fights). sched_barrier(0) per
// pass-2 chunk stops the scheduler from re-batching the shuffles.
__device__ __forceinline__ void hestenes_reg(float (&own)[64], float& w2out, int sweeps) {
  const int lane = threadIdx.x & 63;
  float nrm = 0.f;
#pragma unroll
  for (int i = 0; i < 64; ++i) nrm = fmaf(own[i], own[i], nrm);

  for (int s = 0; s < sweeps; ++s) {
    bool any = false;
    for (int m = 1; m < 64; ++m) {
      // pass 1: partner fetch in chunks of 8 -> dot
      float d0 = 0.f, d1 = 0.f, d2 = 0.f, d3 = 0.f;
#pragma unroll
      for (int base = 0; base < 64; base += 8) {
        float pv[8];
#pragma unroll
        for (int i = 0; i < 8; ++i) pv[i] = __shfl_xor(own[base + i], m);
        d0 = fmaf(own[base + 0], pv[0], d0);
        d1 = fmaf(own[base + 1], pv[1], d1);
        d2 = fmaf(own[base + 2], pv[2], d2);
        d3 = fmaf(own[base + 3], pv[3], d3);
        d0 = fmaf(own[base + 4], pv[4], d0);
        d1 = fmaf(own[base + 5], pv[5], d1);
        d2 = fmaf(own[base + 6], pv[6], d2);
        d3 = fmaf(own[base + 7], pv[7], d3);
      }
      float d = (d0 + d1) + (d2 + d3);
      float pn = __shfl_xor(nrm, m);
      // CSE/remat fence: pass-2 shuffles must be fresh ops (zero runtime cost)
#pragma unroll
      for (int i = 0; i < 64; ++i) asm("" : "+v"(own[i]));
      if (d * d > EPS2_ROT * (nrm * pn)) {     // pair-uniform (bitwise-symmetric)
        any = true;
        bool lo = lane < (lane ^ m);           // exactly one lane of the pair
        float dpp = lo ? nrm : pn;
        float dqq = lo ? pn : nrm;
        float tau = (dqq - dpp) * (0.5f * __builtin_amdgcn_rcpf(d));
        float tt = __builtin_amdgcn_rcpf(fabsf(tau) +
                                         __builtin_amdgcn_sqrtf(fmaf(tau, tau, 1.f)));
        if (tau < 0.f) tt = -tt;
        float c = __builtin_amdgcn_rsqf(fmaf(tt, tt, 1.f));
        float s_ = tt * c;
        float sg = lo ? -s_ : s_;              // lo: c*p - s*q ; hi: c*q + s*p
        // pass 2: re-fetch + rotate, chunked (skipped when pair converged)
#pragma unroll
        for (int base = 0; base < 64; base += 8) {
          float pv[8];
#pragma unroll
          for (int i = 0; i < 8; ++i) pv[i] = __shfl_xor(own[base + i], m);
#pragma unroll
          for (int i = 0; i < 8; ++i)
            own[base + i] = fmaf(sg, pv[i], c * own[base + i]);
          __builtin_amdgcn_sched_barrier(0);
        }
        float td = tt * d;
        nrm += lo ? -td : td;                  // exact Jacobi diagonal update
      }
    }
    if (!__any((int)any)) break;
  }
  float w = 0.f;
#pragma unroll
  for (int i = 0; i < 64; ++i) w = fmaf(own[i], own[i], w);
  w2out = w;
}

// Small-kernel wrapper: wave 0 runs the register Jacobi on the PITCH-72 tile.
__device__ void hestenes_small(Smem& sm, int sweeps) {
  const int t = threadIdx.x;
  if (t < 64) {
    float own[64];
#pragma unroll
    for (int i = 0; i < 64; ++i) own[i] = sm.S0[t * PITCH + i];
    float w2;
    hestenes_reg(own, w2, sweeps);
#pragma unroll
    for (int i = 0; i < 64; ++i) sm.S0[t * PITCH + i] = own[i];
    sm.w2[t] = w2;
  }
  __syncthreads();
}

// ======================================================================
// NEW infrastructure (pitch 68) — batch kernels, 4 matrices per block
// ======================================================================
struct __align__(16) SmemK {      // k1,k2,k3 : 36.1 KB -> 4 blocks/CU
  float A[64*NP];
  float Bop[64*NP];
  float wc[64];
  float red[256];
};
struct __align__(16) SmemK4 {     // k4 : 52.3 KB -> 3 blocks/CU
  float A[64*NP];
  float P[64*NP];
  float Q[64*NP];
  float wc[64];
  float red[256];
};

__device__ __forceinline__ void g2s68(float* dst, const float* __restrict__ src) {
  int t = threadIdx.x;
#pragma unroll
  for (int i = 0; i < 4; ++i) {
    int e4 = t + (i << 8);
    F4 vv = *(const F4*)&src[e4 * 4];
    *(F4*)&dst[(e4 >> 4) * NP + (e4 & 15) * 4] = vv;
  }
  __syncthreads();
}
__device__ __forceinline__ void g2s68s(float* dst, const float* __restrict__ src, float sc) {
  int t = threadIdx.x;
#pragma unroll
  for (int i = 0; i < 4; ++i) {
    int e4 = t + (i << 8);
    F4 vv = *(const F4*)&src[e4 * 4];
#pragma unroll
    for (int m = 0; m < 4; ++m) vv.v[m] *= sc;
    *(F4*)&dst[(e4 >> 4) * NP + (e4 & 15) * 4] = vv;
  }
  __syncthreads();
}

// MODE 0: A <- Bo*A ; 1: A <- A*Bo ; 2: A <- A*Bo^T   (all in-place on A)
template<int MODE>
__device__ void mm68(float* A, const float* Bo) {
  int t = threadIdx.x;
  int R0 = t >> 4;
  if (MODE == 2) {
    int J0 = t & 15;
    float acc[4][4] = {};
    for (int kb = 0; kb < 64; kb += 4) {
      F4 a4[4];
#pragma unroll
      for (int i = 0; i < 4; ++i) a4[i] = *(const F4*)&A[(R0 + 16 * i) * NP + kb];
#pragma unroll
      for (int kk = 0; kk < 4; ++kk) {
        float b[4];
#pragma unroll
        for (int m = 0; m < 4; ++m) b[m] = Bo[(J0 + 16 * m) * NP + kb + kk];
#pragma unroll
        for (int i = 0; i < 4; ++i)
#pragma unroll
          for (int m = 0; m < 4; ++m) acc[i][m] = fmaf(a4[i].v[kk], b[m], acc[i][m]);
      }
    }
    __syncthreads();
#pragma unroll
    for (int i = 0; i < 4; ++i)
#pragma unroll
      for (int m = 0; m < 4; ++m)
        A[(R0 + 16 * i) * NP + J0 + 16 * m] = acc[i][m];
    __syncthreads();
  } else {
    int J = (t & 15) * 4;
    float acc[4][4] = {};
    for (int kb = 0; kb < 64; kb += 4) {
      F4 a4[4], b4[4];
#pragma unroll
      for (int i = 0; i < 4; ++i) {
        const float* L = (MODE == 0) ? Bo : A;
        a4[i] = *(const F4*)&L[(R0 + 16 * i) * NP + kb];
      }
#pragma unroll
      for (int kk = 0; kk < 4; ++kk) {
        const float* Rp = (MODE == 0) ? A : Bo;
        b4[kk] = *(const F4*)&Rp[(kb + kk) * NP + J];
      }
#pragma unroll
      for (int i = 0; i < 4; ++i)
#pragma unroll
        for (int kk = 0; kk < 4; ++kk)
#pragma unroll
          for (int m = 0; m < 4; ++m)
            acc[i][m] = fmaf(a4[i].v[kk], b4[kk].v[m], acc[i][m]);
    }
    __syncthreads();
#pragma unroll
    for (int i = 0; i < 4; ++i) {
      F4 o;
#pragma unroll
      for (int m = 0; m < 4; ++m) o.v[m] = acc[i][m];
      *(F4*)&A[(R0 + 16 * i) * NP + J] = o;
    }
    __syncthreads();
  }
}

__device__ float frob68(const float* A, float* red) {
  int t = threadIdx.x;
  float s = 0.f;
#pragma unroll
  for (int i = 0; i < 4; ++i) {
    int e4 = t + (i << 8);
    F4 vv = *(const F4*)&A[(e4 >> 4) * NP + (e4 & 15) * 4];
#pragma unroll
    for (int m = 0; m < 4; ++m) s = fmaf(vv.v[m], vv.v[m], s);
  }
  red[t] = s;
  __syncthreads();
  for (int o = 128; o; o >>= 1) { if (t < o) red[t] += red[t + o]; __syncthreads(); }
  float f = red[0];
  __syncthreads();
  return f;
}

// Z*Z -> global (row-major 64x64), reads Z (pitch 68), no LDS writes
__device__ void msq_store(const float* Z, float* __restrict__ gout) {
  int t = threadIdx.x;
  int R0 = t >> 4;
  int J = (t & 15) * 4;
  float acc[4][4] = {};
  for (int kb = 0; kb < 64; kb += 4) {
    F4 a4[4], b4[4];
#pragma unroll
    for (int i = 0; i < 4; ++i) a4[i] = *(const F4*)&Z[(R0 + 16 * i) * NP + kb];
#pragma unroll
    for (int kk = 0; kk < 4; ++kk) b4[kk] = *(const F4*)&Z[(kb + kk) * NP + J];
#pragma unroll
    for (int i = 0; i < 4; ++i)
#pragma unroll
      for (int kk = 0; kk < 4; ++kk)
#pragma unroll
        for (int m = 0; m < 4; ++m)
          acc[i][m] = fmaf(a4[i].v[kk], b4[kk].v[m], acc[i][m]);
  }
#pragma unroll
  for (int i = 0; i < 4; ++i) {
    F4 o;
#pragma unroll
    for (int m = 0; m < 4; ++m) o.v[m] = acc[i][m];
    *(F4*)&gout[(R0 + 16 * i) * 64 + J] = o;
  }
}

// ============================ kernels ============================

__global__ __launch_bounds__(256) void kzero(float* ws) {
  int i = blockIdx.x * 256 + threadIdx.x;
  if (i < OFF_BASE) ws[i] = 0.f;
  if (i == 0) ws[OFF_VAR] = 0.f;
}

// Mnh/Mh/Wh/Wc-eig -> P = Wc^{-1/2} Wh, Q = Mh Wc^{1/2}
__global__ KATTR void kprep(const float* __restrict__ weight,
                            const float* __restrict__ M,
                            float* ws) {
  __shared__ Smem sm;
  int t = threadIdx.x;
  g2s(sm.S0, M);
  hestenes_small(sm, SW_SMALL);
  if (t < 64) sm.wc[t] = powf(fmaxf(sm.w2[t], 1e-12f), -1.25f);
  reconT(sm); s2g(ws + SL_MNH, sm.S1);
  if (t < 64) sm.wc[t] = powf(fmaxf(sm.w2[t], 1e-12f), -0.75f);
  reconT(sm); s2g(ws + SL_MH, sm.S1);

  g2s(sm.S0, weight);
  hestenes_small(sm, SW_SMALL);
  if (t < 64) sm.wc[t] = powf(fmaxf(sm.w2[t], 1e-12f), -0.75f);
  reconT(sm); s2g(ws + SL_WH, sm.S1);

  g2s(sm.S0, ws + SL_MNH);
  mmX<1>(sm);
  g2s(sm.S1, ws + SL_MNH);
  mmX<1>(sm);
  hestenes_small(sm, SW_SMALL);
  if (t < 64) sm.wc[t] = powf(fmaxf(sm.w2[t], 1e-12f), -0.75f);
  reconT(sm); s2g(ws + SL_WCH, sm.S1);
  if (t < 64) sm.wc[t] = powf(fmaxf(sm.w2[t], 1e-12f), -1.25f);
  reconT(sm);
  g2s(sm.S0, ws + SL_WH);
  mmX<0>(sm);
  s2g(ws + SL_P, sm.S0);
  g2s(sm.S0, ws + SL_WCH);
  g2s(sm.S1, ws + SL_MH);
  mmX<0>(sm);
  s2g(ws + SL_Q, sm.S0);
}

// Xc_i = Mnh sqrt(X_i) Mnh -> out ; accumulate sum(Xc).  4 matrices/block.
__global__ KATTR void k1(const float* __restrict__ X,
                         float* __restrict__ out, float* ws) {
  __shared__ SmemK sm;
  int t = threadIdx.x;
  int w = t >> 6, lane = t & 63;
  size_t b = blockIdx.x;
  g2s68(sm.Bop, ws + SL_MNH);

  float own[64]; float w2;
  {
    const float* Xm = X + (b * 4 + w) * 4096 + (size_t)lane * 64;  // row lane = col lane (symmetric)
#pragma unroll
    for (int j = 0; j < 16; ++j) {
      F4 r = *(const F4*)&Xm[4 * j];
      own[4 * j + 0] = r.v[0]; own[4 * j + 1] = r.v[1];
      own[4 * j + 2] = r.v[2]; own[4 * j + 3] = r.v[3];
    }
  }
  hestenes_reg(own, w2, SW_BATCH);
  __syncthreads();

  int R0 = t >> 4, J = (t & 15) * 4;
  for (int m = 0; m < 4; ++m) {
    if (w == m) {
#pragma unroll
      for (int j = 0; j < 16; ++j) {
        F4 o = {{own[4 * j], own[4 * j + 1], own[4 * j + 2], own[4 * j + 3]}};
        *(F4*)&sm.A[lane * NP + 4 * j] = o;
      }
      sm.wc[lane] = powf(fmaxf(w2, 1e-12f), -0.75f);   // sqrt: lam^{1/2-2}
    }
    __syncthreads();
    mm68<1>(sm.A, sm.Bop);                              // rows = lam (Mnh u)^T
    // fused recon + epilogue (no LDS round-trip)
    float acc[4][4] = {};
    for (int k = 0; k < 64; ++k) {
      float wck = sm.wc[k];
      float a[4];
#pragma unroll
      for (int i = 0; i < 4; ++i) a[i] = wck * sm.A[k * NP + R0 + 16 * i];
      F4 bb = *(const F4*)&sm.A[k * NP + J];
#pragma unroll
      for (int i = 0; i < 4; ++i)
#pragma unroll
        for (int mc = 0; mc < 4; ++mc) acc[i][mc] = fmaf(a[i], bb.v[mc], acc[i][mc]);
    }
    float* Xc = out + (b * 4 + m) * 4096;
    float* accp = ws + OFF_ACCG + (size_t)((b * 4 + m) & (NPART - 1)) * 4096;
#pragma unroll
    for (int i = 0; i < 4; ++i) {
      F4 o;
#pragma unroll
      for (int mc = 0; mc < 4; ++mc) o.v[mc] = acc[i][mc];
      int base = (R0 + 16 * i) * 64 + J;
      *(F4*)&Xc[base] = o;
#pragma unroll
      for (int mc = 0; mc < 4; ++mc) atomicAdd(accp + base + mc, o.v[mc]);
    }
    __syncthreads();
  }
}

// G0 = mean(Xc); eig -> G0h, G0nh
__global__ KATTR void ksmall2(float* ws, float invB) {
  __shared__ Smem sm;
  int t = threadIdx.x;
#pragma unroll
  for (int i = 0; i < 4; ++i) {
    int e4 = t + (i << 8);
    F4 sum = {{0.f, 0.f, 0.f, 0.f}};
    for (int p = 0; p < NPART; ++p) {
      F4 vv = *(const F4*)&ws[OFF_ACCG + p * 4096 + e4 * 4];
#pragma unroll
      for (int m = 0; m < 4; ++m) sum.v[m] += vv.v[m];
    }
#pragma unroll
    for (int m = 0; m < 4; ++m) sum.v[m] *= invB;
    *(F4*)&sm.S0[(e4 >> 4) * PITCH + (e4 & 15) * 4] = sum;
  }
  __syncthreads();
  hestenes_small(sm, SW_SMALL);
  if (t < 64) sm.wc[t] = powf(fmaxf(sm.w2[t], 1e-12f), -0.75f);
  reconT(sm); s2g(ws + SL_GH, sm.S1);
  if (t < 64) sm.wc[t] = powf(fmaxf(sm.w2[t], 1e-12f), -1.25f);
  reconT(sm); s2g(ws + SL_GNH, sm.S1);
}

// accumulate sum_i log(G0nh Xc_i G0nh).  4 matrices/block.
__global__ KATTR void k2(const float* __restrict__ XcBuf, float* ws) {
  __shared__ SmemK sm;
  int t = threadIdx.x;
  int w = t >> 6, lane = t & 63;
  size_t b = blockIdx.x;
  g2s68(sm.Bop, ws + SL_GNH);

  float own[64]; float w2;
  for (int m = 0; m < 4; ++m) {
    g2s68(sm.A, XcBuf + (b * 4 + m) * 4096);
    mm68<1>(sm.A, sm.Bop);                    // Xc*Gnh
    mm68<0>(sm.A, sm.Bop);                    // Gnh*Xc*Gnh
    if (w == m) {
#pragma unroll
      for (int i = 0; i < 64; ++i) own[i] = sm.A[i * NP + lane];
    }
    __syncthreads();
  }
  hestenes_reg(own, w2, SW_BATCH);
  __syncthreads();

  int R0 = t >> 4, J = (t & 15) * 4;
  for (int m = 0; m < 4; ++m) {
    if (w == m) {
#pragma unroll
      for (int j = 0; j < 16; ++j) {
        F4 o = {{own[4 * j], own[4 * j + 1], own[4 * j + 2], own[4 * j + 3]}};
        *(F4*)&sm.A[lane * NP + 4 * j] = o;
      }
      float s2 = fmaxf(w2, 1e-12f);
      sm.wc[lane] = 0.5f * logf(s2) / s2;     // log(lam)/lam^2
    }
    __syncthreads();
    float acc[4][4] = {};
    for (int k = 0; k < 64; ++k) {
      float wck = sm.wc[k];
      float a[4];
#pragma unroll
      for (int i = 0; i < 4; ++i) a[i] = wck * sm.A[k * NP + R0 + 16 * i];
      F4 bb = *(const F4*)&sm.A[k * NP + J];
#pragma unroll
      for (int i = 0; i < 4; ++i)
#pragma unroll
        for (int mc = 0; mc < 4; ++mc) acc[i][mc] = fmaf(a[i], bb.v[mc], acc[i][mc]);
    }
    float* accp = ws + OFF_ACCT + (size_t)((b * 4 + m) & (NPART - 1)) * 4096;
#pragma unroll
    for (int i = 0; i < 4; ++i) {
      int base = (R0 + 16 * i) * 64 + J;
#pragma unroll
      for (int mc = 0; mc < 4; ++mc) atomicAdd(accp + base + mc, acc[i][mc]);
    }
    __syncthreads();
  }
}

// Tbar = mean ; mean_G = G0h exp(Tbar) G0h ; mnh = mean_G^{-1/2}
__global__ KATTR void ksmall3(float* ws, float invB) {
  __shared__ Smem sm;
  int t = threadIdx.x;
#pragma unroll
  for (int i = 0; i < 4; ++i) {
    int e4 = t + (i << 8);
    F4 sum = {{0.f, 0.f, 0.f, 0.f}};
    for (int p = 0; p < NPART; ++p) {
      F4 vv = *(const F4*)&ws[OFF_ACCT + p * 4096 + e4 * 4];
#pragma unroll
      for (int m = 0; m < 4; ++m) sum.v[m] += vv.v[m];
    }
#pragma unroll
    for (int m = 0; m < 4; ++m) sum.v[m] *= invB;
    *(F4*)&sm.S0[(e4 >> 4) * PITCH + (e4 & 15) * 4] = sum;
  }
  __syncthreads();
  float mu = sqrtf(frob2(sm)) + 1e-3f;
  if (t < 64) sm.S0[t * PITCH + t] += mu;
  __syncthreads();
  hestenes_small(sm, SW_SMALL);
  if (t < 64) {
    float s2 = fmaxf(sm.w2[t], 1e-12f);
    sm.wc[t] = expf(sqrtf(s2) - mu) / s2;
  }
  reconT(sm);
  g2s(sm.S0, ws + SL_GH);
  mmX<1>(sm);
  g2s(sm.S1, ws + SL_GH);
  mmX<1>(sm);
  hestenes_small(sm, SW_SMALL);
  if (t < 64) sm.wc[t] = powf(fmaxf(sm.w2[t], 1e-12f), -1.25f);
  reconT(sm); s2g(ws + SL_MNH2, sm.S1);
}

// T_i = log(mnh Xc_i mnh) (overwrites Xc) ; accumulate ||T||_F^2.  4/block.
__global__ KATTR void k3(float* __restrict__ buf, float* ws) {
  __shared__ SmemK sm;
  int t = threadIdx.x;
  int w = t >> 6, lane = t & 63;
  size_t b = blockIdx.x;
  g2s68(sm.Bop, ws + SL_MNH2);

  float own[64]; float w2;
  for (int m = 0; m < 4; ++m) {
    g2s68(sm.A, buf + (b * 4 + m) * 4096);
    mm68<1>(sm.A, sm.Bop);
    mm68<0>(sm.A, sm.Bop);
    if (w == m) {
#pragma unroll
      for (int i = 0; i < 64; ++i) own[i] = sm.A[i * NP + lane];
    }
    __syncthreads();
  }
  hestenes_reg(own, w2, SW_BATCH);
  __syncthreads();

  int R0 = t >> 4, J = (t & 15) * 4;
  for (int m = 0; m < 4; ++m) {
    if (w == m) {
#pragma unroll
      for (int j = 0; j < 16; ++j) {
        F4 o = {{own[4 * j], own[4 * j + 1], own[4 * j + 2], own[4 * j + 3]}};
        *(F4*)&sm.A[lane * NP + 4 * j] = o;
      }
      float s2 = fmaxf(w2, 1e-12f);
      sm.wc[lane] = 0.5f * logf(s2) / s2;
    }
    __syncthreads();
    float acc[4][4] = {};
    for (int k = 0; k < 64; ++k) {
      float wck = sm.wc[k];
      float a[4];
#pragma unroll
      for (int i = 0; i < 4; ++i) a[i] = wck * sm.A[k * NP + R0 + 16 * i];
      F4 bb = *(const F4*)&sm.A[k * NP + J];
#pragma unroll
      for (int i = 0; i < 4; ++i)
#pragma unroll
        for (int mc = 0; mc < 4; ++mc) acc[i][mc] = fmaf(a[i], bb.v[mc], acc[i][mc]);
    }
    float* Tg = buf + (b * 4 + m) * 4096;
    float ssq = 0.f;
#pragma unroll
    for (int i = 0; i < 4; ++i) {
      F4 o;
#pragma unroll
      for (int mc = 0; mc < 4; ++mc) o.v[mc] = acc[i][mc];
      int base = (R0 + 16 * i) * 64 + J;
      *(F4*)&Tg[base] = o;
#pragma unroll
      for (int mc = 0; mc < 4; ++mc) ssq = fmaf(o.v[mc], o.v[mc], ssq);
    }
    sm.red[t] = ssq;
    __syncthreads();
    for (int o = 128; o; o >>= 1) { if (t < o) sm.red[t] += sm.red[t + o]; __syncthreads(); }
    if (t == 0) atomicAdd(ws + OFF_VAR, sm.red[0]);
    __syncthreads();
  }
}

__global__ void kscale(float* ws, const float* __restrict__ shift, float invB) {
  if (threadIdx.x == 0 && blockIdx.x == 0) {
    float var = ws[OFF_VAR] * invB;
    ws[SL_SC] = shift[0] / sqrtf(var + 1e-5f);
  }
}

// Y_i = (Q exp(scale * P T_i P^T) Q^T)^2 -> buf.  4 matrices/block.
__global__ KATTR void k4(float* __restrict__ buf, float* ws) {
  __shared__ SmemK4 sm;
  int t = threadIdx.x;
  int w = t >> 6, lane = t & 63;
  size_t b = blockIdx.x;
  float sc = ws[SL_SC];
  g2s68(sm.P, ws + SL_P);
  g2s68(sm.Q, ws + SL_Q);

  float own[64]; float w2; float muw = 0.f;
  for (int m = 0; m < 4; ++m) {
    g2s68s(sm.A, buf + (b * 4 + m) * 4096, sc);   // scale*T
    mm68<0>(sm.A, sm.P);                          // P*(scT)
    mm68<2>(sm.A, sm.P);                          // P*(scT)*P^T (symmetric indefinite)
    float f = frob68(sm.A, sm.red);
    if (w == m) {
      muw = sqrtf(f) + 1e-3f;                     // SPD shift
#pragma unroll
      for (int i = 0; i < 64; ++i) {
        float v = sm.A[i * NP + lane];
        own[i] = v + ((i == lane) ? muw : 0.f);
      }
    }
    __syncthreads();
  }
  hestenes_reg(own, w2, SW_BATCH);
  __syncthreads();

  int R0 = t >> 4, J = (t & 15) * 4;
  for (int m = 0; m < 4; ++m) {
    if (w == m) {
#pragma unroll
      for (int j = 0; j < 16; ++j) {
        F4 o = {{own[4 * j], own[4 * j + 1], own[4 * j + 2], own[4 * j + 3]}};
        *(F4*)&sm.A[lane * NP + 4 * j] = o;
      }
      float s2 = fmaxf(w2, 1e-12f);
      sm.wc[lane] = expf(sqrtf(s2) - muw) / s2;
    }
    __syncthreads();
    mm68<2>(sm.A, sm.Q);                          // rows = lam (Q u)^T
    // recon -> sm.P (P is dead after pre-phase): Z = Q E Q^T
    float acc[4][4] = {};
    for (int k = 0; k < 64; ++k) {
      float wck = sm.wc[k];
      float a[4];
#pragma unroll
      for (int i = 0; i < 4; ++i) a[i] = wck * sm.A[k * NP + R0 + 16 * i];
      F4 bb = *(const F4*)&sm.A[k * NP + J];
#pragma unroll
      for (int i = 0; i < 4; ++i)
#pragma unroll
        for (int mc = 0; mc < 4; ++mc) acc[i][mc] = fmaf(a[i], bb.v[mc], acc[i][mc]);
    }
#pragma unroll
    for (int i = 0; i < 4; ++i) {
      F4 o;
#pragma unroll
      for (int mc = 0; mc < 4; ++mc) o.v[mc] = acc[i][mc];
      *(F4*)&sm.P[(R0 + 16 * i) * NP + J] = o;
    }
    __syncthreads();
    msq_store(sm.P, buf + (b * 4 + m) * 4096);    // Y = Z*Z -> global
    __syncthreads();
  }
}

extern "C" void kernel_launch(void* const* d_in, const int* in_sizes, int n_in,
                              void* d_out, int out_size, void* d_ws, size_t ws_size,
                              hipStream_t stream) {
  const float* X      = (const float*)d_in[0];
  const float* weight = (const float*)d_in[1];
  const float* M      = (const float*)d_in[2];
  const float* shift  = (const float*)d_in[3];
  float* out = (float*)d_out;
  float* ws  = (float*)d_ws;
  int B = in_sizes[0] / 4096;      // 4096 matrices of 64x64
  float invB = 1.f / (float)B;
  int G = B / 4;                   // 4 matrices per block

  hipLaunchKernelGGL(kzero,   dim3(OFF_BASE / 256), dim3(256), 0, stream, ws);
  hipLaunchKernelGGL(kprep,   dim3(1), dim3(256), 0, stream, weight, M, ws);
  hipLaunchKernelGGL(k1,      dim3(G), dim3(256), 0, stream, X, out, ws);
  hipLaunchKernelGGL(ksmall2, dim3(1), dim3(256), 0, stream, ws, invB);
  hipLaunchKernelGGL(k2,      dim3(G), dim3(256), 0, stream, out, ws);
  hipLaunchKernelGGL(ksmall3, dim3(1), dim3(256), 0, stream, ws, invB);
  hipLaunchKernelGGL(k3,      dim3(G), dim3(256), 0, stream, out, ws);
  hipLaunchKernelGGL(kscale,  dim3(1), dim3(64), 0, stream, ws, shift, invB);
  hipLaunchKernelGGL(k4,      dim3(G), dim3(256), 0, stream, out, ws);
}

// Round 7
// 14473.936 us; speedup vs baseline: 1.0178x; 1.0178x over previous
//
#include <hip/hip_runtime.h>
#include <math.h>

#define PITCH 72      // old layout (small kernels only)
#define NP 68         // new pitch: word(row r, col c) = 68r+c ; bank = (4r+c) mod 32
#define SW_BATCH 12
#define SW_SMALL 10
#define NPART 32
#define EPS2_ROT 1e-12f   // (1e-6)^2 : threshold compared on d^2

#define KATTR __attribute__((amdgpu_flat_work_group_size(256, 256), amdgpu_waves_per_eu(2, 8)))

// ---- workspace float-offsets ----
#define OFF_ACCG 0
#define OFF_ACCT (NPART*4096)
#define OFF_BASE (2*NPART*4096)
#define SL_MNH  (OFF_BASE + 0*4096)
#define SL_MH   (OFF_BASE + 1*4096)
#define SL_WH   (OFF_BASE + 2*4096)
#define SL_P    (OFF_BASE + 3*4096)
#define SL_Q    (OFF_BASE + 4*4096)
#define SL_GH   (OFF_BASE + 5*4096)
#define SL_GNH  (OFF_BASE + 6*4096)
#define SL_MNH2 (OFF_BASE + 7*4096)
#define SL_WCH  (OFF_BASE + 8*4096)
#define OFF_VAR (OFF_BASE + 9*4096)
#define SL_SC   (OFF_BASE + 9*4096 + 1)

struct __align__(16) F4 { float v[4]; };

// ======================================================================
// OLD infrastructure (PITCH 72) — used only by the 1-block small kernels
// ======================================================================
struct __align__(16) Smem {
  float S0[64*PITCH];
  float S1[64*PITCH];
  float w2[64];
  float wc[64];
  float red[256];
};

__device__ __forceinline__ void g2s(float* dst, const float* __restrict__ src) {
  int t = threadIdx.x;
#pragma unroll
  for (int i = 0; i < 4; ++i) {
    int e4 = t + (i << 8);
    F4 vv = *(const F4*)&src[e4 * 4];
    *(F4*)&dst[(e4 >> 4) * PITCH + (e4 & 15) * 4] = vv;
  }
  __syncthreads();
}
__device__ __forceinline__ void s2g(float* __restrict__ dst, const float* src) {
  int t = threadIdx.x;
#pragma unroll
  for (int i = 0; i < 4; ++i) {
    int e4 = t + (i << 8);
    F4 vv = *(const F4*)&src[(e4 >> 4) * PITCH + (e4 & 15) * 4];
    *(F4*)&dst[e4 * 4] = vv;
  }
  __syncthreads();
}

template<int MODE>   // 0: S0<-S1*S0 ; 1: S0<-S0*S1
__device__ void mmX(Smem& sm) {
  int t = threadIdx.x;
  int R0 = t >> 4;
  int J = (t & 15) * 4;
  float acc[4][4] = {};
  for (int kb = 0; kb < 64; kb += 4) {
    F4 a4[4], b4[4];
#pragma unroll
    for (int i = 0; i < 4; ++i) {
      const float* L = (MODE == 0) ? sm.S1 : sm.S0;
      a4[i] = *(const F4*)&L[(R0 + 16 * i) * PITCH + kb];
    }
#pragma unroll
    for (int kk = 0; kk < 4; ++kk) {
      const float* Rp = (MODE == 0) ? sm.S0 : sm.S1;
      b4[kk] = *(const F4*)&Rp[(kb + kk) * PITCH + J];
    }
#pragma unroll
    for (int i = 0; i < 4; ++i)
#pragma unroll
      for (int kk = 0; kk < 4; ++kk)
#pragma unroll
        for (int m = 0; m < 4; ++m)
          acc[i][m] = fmaf(a4[i].v[kk], b4[kk].v[m], acc[i][m]);
  }
  __syncthreads();
#pragma unroll
  for (int i = 0; i < 4; ++i) {
    F4 o;
#pragma unroll
    for (int m = 0; m < 4; ++m) o.v[m] = acc[i][m];
    *(F4*)&sm.S0[(R0 + 16 * i) * PITCH + J] = o;
  }
  __syncthreads();
}

__device__ void reconT(Smem& sm) {
  __syncthreads();
  int t = threadIdx.x;
  int R0 = t >> 4;
  int J = (t & 15) * 4;
  float acc[4][4] = {};
  for (int k = 0; k < 64; ++k) {
    float w = sm.wc[k];
    float a[4];
#pragma unroll
    for (int i = 0; i < 4; ++i) a[i] = w * sm.S0[k * PITCH + R0 + 16 * i];
    F4 b = *(const F4*)&sm.S0[k * PITCH + J];
#pragma unroll
    for (int i = 0; i < 4; ++i)
#pragma unroll
      for (int m = 0; m < 4; ++m) acc[i][m] = fmaf(a[i], b.v[m], acc[i][m]);
  }
#pragma unroll
  for (int i = 0; i < 4; ++i) {
    F4 o;
#pragma unroll
    for (int m = 0; m < 4; ++m) o.v[m] = acc[i][m];
    *(F4*)&sm.S1[(R0 + 16 * i) * PITCH + J] = o;
  }
  __syncthreads();
}

__device__ float frob2(Smem& sm) {
  int t = threadIdx.x;
  float s = 0.f;
#pragma unroll
  for (int i = 0; i < 4; ++i) {
    int e4 = t + (i << 8);
    F4 vv = *(const F4*)&sm.S0[(e4 >> 4) * PITCH + (e4 & 15) * 4];
#pragma unroll
    for (int m = 0; m < 4; ++m) s = fmaf(vv.v[m], vv.v[m], s);
  }
  sm.red[t] = s;
  __syncthreads();
  for (int o = 128; o; o >>= 1) { if (t < o) sm.red[t] += sm.red[t + o]; __syncthreads(); }
  float f = sm.red[0];
  __syncthreads();
  return f;
}

// ---------- register-resident wave-synchronous one-sided Jacobi ----------
// lane l holds column l (= row l of the symmetric input) in own[64].
// XOR ordering: round m pairs lane l with lane l^m (m=1..63). Both lanes
// compute bitwise-identical d (products commute, same summation order).
// EXPLICIT 2-PASS structure, peak liveness ~own[64]+8 (<=~90 VGPR) by design:
//   pass 1: chunked shfl -> dot (pv dies per 8-chunk)
//   pass 2: only if rotating, chunked shfl -> rotate (pv dies per 8-chunk)
// TWO compiler legalities must be blocked (R6 post-mortem):
//   - CSE: pass-2 shuffles of unchanged own[] would merge with pass-1 ->
//     64-live pv. Blocked by the empty asm "+v" fence (new SSA values).
//   - Scheduler DS-clustering: the latency-hiding heuristic hoists all 64
//     pass-1 shuffles above the FMAs -> 64-live pv (R6: scratch thrash,
//     k3 43.7ms). Blocked by sched_barrier(0) after EVERY chunk, both passes.
__device__ __forceinline__ void hestenes_reg(float (&own)[64], float& w2out, int sweeps) {
  const int lane = threadIdx.x & 63;
  float nrm = 0.f;
#pragma unroll
  for (int i = 0; i < 64; ++i) nrm = fmaf(own[i], own[i], nrm);

  for (int s = 0; s < sweeps; ++s) {
    bool any = false;
    for (int m = 1; m < 64; ++m) {
      // pass 1: partner fetch in chunks of 8 -> dot
      float d0 = 0.f, d1 = 0.f, d2 = 0.f, d3 = 0.f;
#pragma unroll
      for (int base = 0; base < 64; base += 8) {
        float pv[8];
#pragma unroll
        for (int i = 0; i < 8; ++i) pv[i] = __shfl_xor(own[base + i], m);
        d0 = fmaf(own[base + 0], pv[0], d0);
        d1 = fmaf(own[base + 1], pv[1], d1);
        d2 = fmaf(own[base + 2], pv[2], d2);
        d3 = fmaf(own[base + 3], pv[3], d3);
        d0 = fmaf(own[base + 4], pv[4], d0);
        d1 = fmaf(own[base + 5], pv[5], d1);
        d2 = fmaf(own[base + 6], pv[6], d2);
        d3 = fmaf(own[base + 7], pv[7], d3);
        __builtin_amdgcn_sched_barrier(0);   // keep chunk liveness at 8
      }
      float d = (d0 + d1) + (d2 + d3);
      float pn = __shfl_xor(nrm, m);
      // CSE fence: pass-2 shuffles must be fresh ops (zero runtime cost)
#pragma unroll
      for (int i = 0; i < 64; ++i) asm("" : "+v"(own[i]));
      if (d * d > EPS2_ROT * (nrm * pn)) {     // pair-uniform (bitwise-symmetric)
        any = true;
        bool lo = lane < (lane ^ m);           // exactly one lane of the pair
        float dpp = lo ? nrm : pn;
        float dqq = lo ? pn : nrm;
        float tau = (dqq - dpp) * (0.5f * __builtin_amdgcn_rcpf(d));
        float tt = __builtin_amdgcn_rcpf(fabsf(tau) +
                                         __builtin_amdgcn_sqrtf(fmaf(tau, tau, 1.f)));
        if (tau < 0.f) tt = -tt;
        float c = __builtin_amdgcn_rsqf(fmaf(tt, tt, 1.f));
        float s_ = tt * c;
        float sg = lo ? -s_ : s_;              // lo: c*p - s*q ; hi: c*q + s*p
        // pass 2: re-fetch + rotate, chunked (skipped when pair converged)
#pragma unroll
        for (int base = 0; base < 64; base += 8) {
          float pv[8];
#pragma unroll
          for (int i = 0; i < 8; ++i) pv[i] = __shfl_xor(own[base + i], m);
#pragma unroll
          for (int i = 0; i < 8; ++i)
            own[base + i] = fmaf(sg, pv[i], c * own[base + i]);
          __builtin_amdgcn_sched_barrier(0);
        }
        float td = tt * d;
        nrm += lo ? -td : td;                  // exact Jacobi diagonal update
      }
    }
    if (!__any((int)any)) break;
  }
  float w = 0.f;
#pragma unroll
  for (int i = 0; i < 64; ++i) w = fmaf(own[i], own[i], w);
  w2out = w;
}

// Small-kernel wrapper: wave 0 runs the register Jacobi on the PITCH-72 tile.
__device__ void hestenes_small(Smem& sm, int sweeps) {
  const int t = threadIdx.x;
  if (t < 64) {
    float own[64];
#pragma unroll
    for (int i = 0; i < 64; ++i) own[i] = sm.S0[t * PITCH + i];
    float w2;
    hestenes_reg(own, w2, sweeps);
#pragma unroll
    for (int i = 0; i < 64; ++i) sm.S0[t * PITCH + i] = own[i];
    sm.w2[t] = w2;
  }
  __syncthreads();
}

// ======================================================================
// NEW infrastructure (pitch 68) — batch kernels, 4 matrices per block
// ======================================================================
struct __align__(16) SmemK {      // k1,k2,k3 : 36.1 KB -> 4 blocks/CU
  float A[64*NP];
  float Bop[64*NP];
  float wc[64];
  float red[256];
};
struct __align__(16) SmemK4 {     // k4 : 52.3 KB -> 3 blocks/CU
  float A[64*NP];
  float P[64*NP];
  float Q[64*NP];
  float wc[64];
  float red[256];
};

__device__ __forceinline__ void g2s68(float* dst, const float* __restrict__ src) {
  int t = threadIdx.x;
#pragma unroll
  for (int i = 0; i < 4; ++i) {
    int e4 = t + (i << 8);
    F4 vv = *(const F4*)&src[e4 * 4];
    *(F4*)&dst[(e4 >> 4) * NP + (e4 & 15) * 4] = vv;
  }
  __syncthreads();
}
__device__ __forceinline__ void g2s68s(float* dst, const float* __restrict__ src, float sc) {
  int t = threadIdx.x;
#pragma unroll
  for (int i = 0; i < 4; ++i) {
    int e4 = t + (i << 8);
    F4 vv = *(const F4*)&src[e4 * 4];
#pragma unroll
    for (int m = 0; m < 4; ++m) vv.v[m] *= sc;
    *(F4*)&dst[(e4 >> 4) * NP + (e4 & 15) * 4] = vv;
  }
  __syncthreads();
}

// MODE 0: A <- Bo*A ; 1: A <- A*Bo ; 2: A <- A*Bo^T   (all in-place on A)
template<int MODE>
__device__ void mm68(float* A, const float* Bo) {
  int t = threadIdx.x;
  int R0 = t >> 4;
  if (MODE == 2) {
    int J0 = t & 15;
    float acc[4][4] = {};
    for (int kb = 0; kb < 64; kb += 4) {
      F4 a4[4];
#pragma unroll
      for (int i = 0; i < 4; ++i) a4[i] = *(const F4*)&A[(R0 + 16 * i) * NP + kb];
#pragma unroll
      for (int kk = 0; kk < 4; ++kk) {
        float b[4];
#pragma unroll
        for (int m = 0; m < 4; ++m) b[m] = Bo[(J0 + 16 * m) * NP + kb + kk];
#pragma unroll
        for (int i = 0; i < 4; ++i)
#pragma unroll
          for (int m = 0; m < 4; ++m) acc[i][m] = fmaf(a4[i].v[kk], b[m], acc[i][m]);
      }
    }
    __syncthreads();
#pragma unroll
    for (int i = 0; i < 4; ++i)
#pragma unroll
      for (int m = 0; m < 4; ++m)
        A[(R0 + 16 * i) * NP + J0 + 16 * m] = acc[i][m];
    __syncthreads();
  } else {
    int J = (t & 15) * 4;
    float acc[4][4] = {};
    for (int kb = 0; kb < 64; kb += 4) {
      F4 a4[4], b4[4];
#pragma unroll
      for (int i = 0; i < 4; ++i) {
        const float* L = (MODE == 0) ? Bo : A;
        a4[i] = *(const F4*)&L[(R0 + 16 * i) * NP + kb];
      }
#pragma unroll
      for (int kk = 0; kk < 4; ++kk) {
        const float* Rp = (MODE == 0) ? A : Bo;
        b4[kk] = *(const F4*)&Rp[(kb + kk) * NP + J];
      }
#pragma unroll
      for (int i = 0; i < 4; ++i)
#pragma unroll
        for (int kk = 0; kk < 4; ++kk)
#pragma unroll
          for (int m = 0; m < 4; ++m)
            acc[i][m] = fmaf(a4[i].v[kk], b4[kk].v[m], acc[i][m]);
    }
    __syncthreads();
#pragma unroll
    for (int i = 0; i < 4; ++i) {
      F4 o;
#pragma unroll
      for (int m = 0; m < 4; ++m) o.v[m] = acc[i][m];
      *(F4*)&A[(R0 + 16 * i) * NP + J] = o;
    }
    __syncthreads();
  }
}

__device__ float frob68(const float* A, float* red) {
  int t = threadIdx.x;
  float s = 0.f;
#pragma unroll
  for (int i = 0; i < 4; ++i) {
    int e4 = t + (i << 8);
    F4 vv = *(const F4*)&A[(e4 >> 4) * NP + (e4 & 15) * 4];
#pragma unroll
    for (int m = 0; m < 4; ++m) s = fmaf(vv.v[m], vv.v[m], s);
  }
  red[t] = s;
  __syncthreads();
  for (int o = 128; o; o >>= 1) { if (t < o) red[t] += red[t + o]; __syncthreads(); }
  float f = red[0];
  __syncthreads();
  return f;
}

// Z*Z -> global (row-major 64x64), reads Z (pitch 68), no LDS writes
__device__ void msq_store(const float* Z, float* __restrict__ gout) {
  int t = threadIdx.x;
  int R0 = t >> 4;
  int J = (t & 15) * 4;
  float acc[4][4] = {};
  for (int kb = 0; kb < 64; kb += 4) {
    F4 a4[4], b4[4];
#pragma unroll
    for (int i = 0; i < 4; ++i) a4[i] = *(const F4*)&Z[(R0 + 16 * i) * NP + kb];
#pragma unroll
    for (int kk = 0; kk < 4; ++kk) b4[kk] = *(const F4*)&Z[(kb + kk) * NP + J];
#pragma unroll
    for (int i = 0; i < 4; ++i)
#pragma unroll
      for (int kk = 0; kk < 4; ++kk)
#pragma unroll
        for (int m = 0; m < 4; ++m)
          acc[i][m] = fmaf(a4[i].v[kk], b4[kk].v[m], acc[i][m]);
  }
#pragma unroll
  for (int i = 0; i < 4; ++i) {
    F4 o;
#pragma unroll
    for (int m = 0; m < 4; ++m) o.v[m] = acc[i][m];
    *(F4*)&gout[(R0 + 16 * i) * 64 + J] = o;
  }
}

// ============================ kernels ============================

__global__ __launch_bounds__(256) void kzero(float* ws) {
  int i = blockIdx.x * 256 + threadIdx.x;
  if (i < OFF_BASE) ws[i] = 0.f;
  if (i == 0) ws[OFF_VAR] = 0.f;
}

// Mnh/Mh/Wh/Wc-eig -> P = Wc^{-1/2} Wh, Q = Mh Wc^{1/2}
__global__ KATTR void kprep(const float* __restrict__ weight,
                            const float* __restrict__ M,
                            float* ws) {
  __shared__ Smem sm;
  int t = threadIdx.x;
  g2s(sm.S0, M);
  hestenes_small(sm, SW_SMALL);
  if (t < 64) sm.wc[t] = powf(fmaxf(sm.w2[t], 1e-12f), -1.25f);
  reconT(sm); s2g(ws + SL_MNH, sm.S1);
  if (t < 64) sm.wc[t] = powf(fmaxf(sm.w2[t], 1e-12f), -0.75f);
  reconT(sm); s2g(ws + SL_MH, sm.S1);

  g2s(sm.S0, weight);
  hestenes_small(sm, SW_SMALL);
  if (t < 64) sm.wc[t] = powf(fmaxf(sm.w2[t], 1e-12f), -0.75f);
  reconT(sm); s2g(ws + SL_WH, sm.S1);

  g2s(sm.S0, ws + SL_MNH);
  mmX<1>(sm);
  g2s(sm.S1, ws + SL_MNH);
  mmX<1>(sm);
  hestenes_small(sm, SW_SMALL);
  if (t < 64) sm.wc[t] = powf(fmaxf(sm.w2[t], 1e-12f), -0.75f);
  reconT(sm); s2g(ws + SL_WCH, sm.S1);
  if (t < 64) sm.wc[t] = powf(fmaxf(sm.w2[t], 1e-12f), -1.25f);
  reconT(sm);
  g2s(sm.S0, ws + SL_WH);
  mmX<0>(sm);
  s2g(ws + SL_P, sm.S0);
  g2s(sm.S0, ws + SL_WCH);
  g2s(sm.S1, ws + SL_MH);
  mmX<0>(sm);
  s2g(ws + SL_Q, sm.S0);
}

// Xc_i = Mnh sqrt(X_i) Mnh -> out ; accumulate sum(Xc).  4 matrices/block.
__global__ KATTR void k1(const float* __restrict__ X,
                         float* __restrict__ out, float* ws) {
  __shared__ SmemK sm;
  int t = threadIdx.x;
  int w = t >> 6, lane = t & 63;
  size_t b = blockIdx.x;
  g2s68(sm.Bop, ws + SL_MNH);

  float own[64]; float w2;
  {
    const float* Xm = X + (b * 4 + w) * 4096 + (size_t)lane * 64;  // row lane = col lane (symmetric)
#pragma unroll
    for (int j = 0; j < 16; ++j) {
      F4 r = *(const F4*)&Xm[4 * j];
      own[4 * j + 0] = r.v[0]; own[4 * j + 1] = r.v[1];
      own[4 * j + 2] = r.v[2]; own[4 * j + 3] = r.v[3];
    }
  }
  hestenes_reg(own, w2, SW_BATCH);
  __syncthreads();

  int R0 = t >> 4, J = (t & 15) * 4;
  for (int m = 0; m < 4; ++m) {
    if (w == m) {
#pragma unroll
      for (int j = 0; j < 16; ++j) {
        F4 o = {{own[4 * j], own[4 * j + 1], own[4 * j + 2], own[4 * j + 3]}};
        *(F4*)&sm.A[lane * NP + 4 * j] = o;
      }
      sm.wc[lane] = powf(fmaxf(w2, 1e-12f), -0.75f);   // sqrt: lam^{1/2-2}
    }
    __syncthreads();
    mm68<1>(sm.A, sm.Bop);                              // rows = lam (Mnh u)^T
    // fused recon + epilogue (no LDS round-trip)
    float acc[4][4] = {};
    for (int k = 0; k < 64; ++k) {
      float wck = sm.wc[k];
      float a[4];
#pragma unroll
      for (int i = 0; i < 4; ++i) a[i] = wck * sm.A[k * NP + R0 + 16 * i];
      F4 bb = *(const F4*)&sm.A[k * NP + J];
#pragma unroll
      for (int i = 0; i < 4; ++i)
#pragma unroll
        for (int mc = 0; mc < 4; ++mc) acc[i][mc] = fmaf(a[i], bb.v[mc], acc[i][mc]);
    }
    float* Xc = out + (b * 4 + m) * 4096;
    float* accp = ws + OFF_ACCG + (size_t)((b * 4 + m) & (NPART - 1)) * 4096;
#pragma unroll
    for (int i = 0; i < 4; ++i) {
      F4 o;
#pragma unroll
      for (int mc = 0; mc < 4; ++mc) o.v[mc] = acc[i][mc];
      int base = (R0 + 16 * i) * 64 + J;
      *(F4*)&Xc[base] = o;
#pragma unroll
      for (int mc = 0; mc < 4; ++mc) atomicAdd(accp + base + mc, o.v[mc]);
    }
    __syncthreads();
  }
}

// G0 = mean(Xc); eig -> G0h, G0nh
__global__ KATTR void ksmall2(float* ws, float invB) {
  __shared__ Smem sm;
  int t = threadIdx.x;
#pragma unroll
  for (int i = 0; i < 4; ++i) {
    int e4 = t + (i << 8);
    F4 sum = {{0.f, 0.f, 0.f, 0.f}};
    for (int p = 0; p < NPART; ++p) {
      F4 vv = *(const F4*)&ws[OFF_ACCG + p * 4096 + e4 * 4];
#pragma unroll
      for (int m = 0; m < 4; ++m) sum.v[m] += vv.v[m];
    }
#pragma unroll
    for (int m = 0; m < 4; ++m) sum.v[m] *= invB;
    *(F4*)&sm.S0[(e4 >> 4) * PITCH + (e4 & 15) * 4] = sum;
  }
  __syncthreads();
  hestenes_small(sm, SW_SMALL);
  if (t < 64) sm.wc[t] = powf(fmaxf(sm.w2[t], 1e-12f), -0.75f);
  reconT(sm); s2g(ws + SL_GH, sm.S1);
  if (t < 64) sm.wc[t] = powf(fmaxf(sm.w2[t], 1e-12f), -1.25f);
  reconT(sm); s2g(ws + SL_GNH, sm.S1);
}

// accumulate sum_i log(G0nh Xc_i G0nh).  4 matrices/block.
__global__ KATTR void k2(const float* __restrict__ XcBuf, float* ws) {
  __shared__ SmemK sm;
  int t = threadIdx.x;
  int w = t >> 6, lane = t & 63;
  size_t b = blockIdx.x;
  g2s68(sm.Bop, ws + SL_GNH);

  float own[64]; float w2;
  for (int m = 0; m < 4; ++m) {
    g2s68(sm.A, XcBuf + (b * 4 + m) * 4096);
    mm68<1>(sm.A, sm.Bop);                    // Xc*Gnh
    mm68<0>(sm.A, sm.Bop);                    // Gnh*Xc*Gnh
    if (w == m) {
#pragma unroll
      for (int i = 0; i < 64; ++i) own[i] = sm.A[i * NP + lane];
    }
    __syncthreads();
  }
  hestenes_reg(own, w2, SW_BATCH);
  __syncthreads();

  int R0 = t >> 4, J = (t & 15) * 4;
  for (int m = 0; m < 4; ++m) {
    if (w == m) {
#pragma unroll
      for (int j = 0; j < 16; ++j) {
        F4 o = {{own[4 * j], own[4 * j + 1], own[4 * j + 2], own[4 * j + 3]}};
        *(F4*)&sm.A[lane * NP + 4 * j] = o;
      }
      float s2 = fmaxf(w2, 1e-12f);
      sm.wc[lane] = 0.5f * logf(s2) / s2;     // log(lam)/lam^2
    }
    __syncthreads();
    float acc[4][4] = {};
    for (int k = 0; k < 64; ++k) {
      float wck = sm.wc[k];
      float a[4];
#pragma unroll
      for (int i = 0; i < 4; ++i) a[i] = wck * sm.A[k * NP + R0 + 16 * i];
      F4 bb = *(const F4*)&sm.A[k * NP + J];
#pragma unroll
      for (int i = 0; i < 4; ++i)
#pragma unroll
        for (int mc = 0; mc < 4; ++mc) acc[i][mc] = fmaf(a[i], bb.v[mc], acc[i][mc]);
    }
    float* accp = ws + OFF_ACCT + (size_t)((b * 4 + m) & (NPART - 1)) * 4096;
#pragma unroll
    for (int i = 0; i < 4; ++i) {
      int base = (R0 + 16 * i) * 64 + J;
#pragma unroll
      for (int mc = 0; mc < 4; ++mc) atomicAdd(accp + base + mc, acc[i][mc]);
    }
    __syncthreads();
  }
}

// Tbar = mean ; mean_G = G0h exp(Tbar) G0h ; mnh = mean_G^{-1/2}
__global__ KATTR void ksmall3(float* ws, float invB) {
  __shared__ Smem sm;
  int t = threadIdx.x;
#pragma unroll
  for (int i = 0; i < 4; ++i) {
    int e4 = t + (i << 8);
    F4 sum = {{0.f, 0.f, 0.f, 0.f}};
    for (int p = 0; p < NPART; ++p) {
      F4 vv = *(const F4*)&ws[OFF_ACCT + p * 4096 + e4 * 4];
#pragma unroll
      for (int m = 0; m < 4; ++m) sum.v[m] += vv.v[m];
    }
#pragma unroll
    for (int m = 0; m < 4; ++m) sum.v[m] *= invB;
    *(F4*)&sm.S0[(e4 >> 4) * PITCH + (e4 & 15) * 4] = sum;
  }
  __syncthreads();
  float mu = sqrtf(frob2(sm)) + 1e-3f;
  if (t < 64) sm.S0[t * PITCH + t] += mu;
  __syncthreads();
  hestenes_small(sm, SW_SMALL);
  if (t < 64) {
    float s2 = fmaxf(sm.w2[t], 1e-12f);
    sm.wc[t] = expf(sqrtf(s2) - mu) / s2;
  }
  reconT(sm);
  g2s(sm.S0, ws + SL_GH);
  mmX<1>(sm);
  g2s(sm.S1, ws + SL_GH);
  mmX<1>(sm);
  hestenes_small(sm, SW_SMALL);
  if (t < 64) sm.wc[t] = powf(fmaxf(sm.w2[t], 1e-12f), -1.25f);
  reconT(sm); s2g(ws + SL_MNH2, sm.S1);
}

// T_i = log(mnh Xc_i mnh) (overwrites Xc) ; accumulate ||T||_F^2.  4/block.
__global__ KATTR void k3(float* __restrict__ buf, float* ws) {
  __shared__ SmemK sm;
  int t = threadIdx.x;
  int w = t >> 6, lane = t & 63;
  size_t b = blockIdx.x;
  g2s68(sm.Bop, ws + SL_MNH2);

  float own[64]; float w2;
  for (int m = 0; m < 4; ++m) {
    g2s68(sm.A, buf + (b * 4 + m) * 4096);
    mm68<1>(sm.A, sm.Bop);
    mm68<0>(sm.A, sm.Bop);
    if (w == m) {
#pragma unroll
      for (int i = 0; i < 64; ++i) own[i] = sm.A[i * NP + lane];
    }
    __syncthreads();
  }
  hestenes_reg(own, w2, SW_BATCH);
  __syncthreads();

  int R0 = t >> 4, J = (t & 15) * 4;
  for (int m = 0; m < 4; ++m) {
    if (w == m) {
#pragma unroll
      for (int j = 0; j < 16; ++j) {
        F4 o = {{own[4 * j], own[4 * j + 1], own[4 * j + 2], own[4 * j + 3]}};
        *(F4*)&sm.A[lane * NP + 4 * j] = o;
      }
      float s2 = fmaxf(w2, 1e-12f);
      sm.wc[lane] = 0.5f * logf(s2) / s2;
    }
    __syncthreads();
    float acc[4][4] = {};
    for (int k = 0; k < 64; ++k) {
      float wck = sm.wc[k];
      float a[4];
#pragma unroll
      for (int i = 0; i < 4; ++i) a[i] = wck * sm.A[k * NP + R0 + 16 * i];
      F4 bb = *(const F4*)&sm.A[k * NP + J];
#pragma unroll
      for (int i = 0; i < 4; ++i)
#pragma unroll
        for (int mc = 0; mc < 4; ++mc) acc[i][mc] = fmaf(a[i], bb.v[mc], acc[i][mc]);
    }
    float* Tg = buf + (b * 4 + m) * 4096;
    float ssq = 0.f;
#pragma unroll
    for (int i = 0; i < 4; ++i) {
      F4 o;
#pragma unroll
      for (int mc = 0; mc < 4; ++mc) o.v[mc] = acc[i][mc];
      int base = (R0 + 16 * i) * 64 + J;
      *(F4*)&Tg[base] = o;
#pragma unroll
      for (int mc = 0; mc < 4; ++mc) ssq = fmaf(o.v[mc], o.v[mc], ssq);
    }
    sm.red[t] = ssq;
    __syncthreads();
    for (int o = 128; o; o >>= 1) { if (t < o) sm.red[t] += sm.red[t + o]; __syncthreads(); }
    if (t == 0) atomicAdd(ws + OFF_VAR, sm.red[0]);
    __syncthreads();
  }
}

__global__ void kscale(float* ws, const float* __restrict__ shift, float invB) {
  if (threadIdx.x == 0 && blockIdx.x == 0) {
    float var = ws[OFF_VAR] * invB;
    ws[SL_SC] = shift[0] / sqrtf(var + 1e-5f);
  }
}

// Y_i = (Q exp(scale * P T_i P^T) Q^T)^2 -> buf.  4 matrices/block.
__global__ KATTR void k4(float* __restrict__ buf, float* ws) {
  __shared__ SmemK4 sm;
  int t = threadIdx.x;
  int w = t >> 6, lane = t & 63;
  size_t b = blockIdx.x;
  float sc = ws[SL_SC];
  g2s68(sm.P, ws + SL_P);
  g2s68(sm.Q, ws + SL_Q);

  float own[64]; float w2; float muw = 0.f;
  for (int m = 0; m < 4; ++m) {
    g2s68s(sm.A, buf + (b * 4 + m) * 4096, sc);   // scale*T
    mm68<0>(sm.A, sm.P);                          // P*(scT)
    mm68<2>(sm.A, sm.P);                          // P*(scT)*P^T (symmetric indefinite)
    float f = frob68(sm.A, sm.red);
    if (w == m) {
      muw = sqrtf(f) + 1e-3f;                     // SPD shift
#pragma unroll
      for (int i = 0; i < 64; ++i) {
        float v = sm.A[i * NP + lane];
        own[i] = v + ((i == lane) ? muw : 0.f);
      }
    }
    __syncthreads();
  }
  hestenes_reg(own, w2, SW_BATCH);
  __syncthreads();

  int R0 = t >> 4, J = (t & 15) * 4;
  for (int m = 0; m < 4; ++m) {
    if (w == m) {
#pragma unroll
      for (int j = 0; j < 16; ++j) {
        F4 o = {{own[4 * j], own[4 * j + 1], own[4 * j + 2], own[4 * j + 3]}};
        *(F4*)&sm.A[lane * NP + 4 * j] = o;
      }
      float s2 = fmaxf(w2, 1e-12f);
      sm.wc[lane] = expf(sqrtf(s2) - muw) / s2;
    }
    __syncthreads();
    mm68<2>(sm.A, sm.Q);                          // rows = lam (Q u)^T
    // recon -> sm.P (P is dead after pre-phase): Z = Q E Q^T
    float acc[4][4] = {};
    for (int k = 0; k < 64; ++k) {
      float wck = sm.wc[k];
      float a[4];
#pragma unroll
      for (int i = 0; i < 4; ++i) a[i] = wck * sm.A[k * NP + R0 + 16 * i];
      F4 bb = *(const F4*)&sm.A[k * NP + J];
#pragma unroll
      for (int i = 0; i < 4; ++i)
#pragma unroll
        for (int mc = 0; mc < 4; ++mc) acc[i][mc] = fmaf(a[i], bb.v[mc], acc[i][mc]);
    }
#pragma unroll
    for (int i = 0; i < 4; ++i) {
      F4 o;
#pragma unroll
      for (int mc = 0; mc < 4; ++mc) o.v[mc] = acc[i][mc];
      *(F4*)&sm.P[(R0 + 16 * i) * NP + J] = o;
    }
    __syncthreads();
    msq_store(sm.P, buf + (b * 4 + m) * 4096);    // Y = Z*Z -> global
    __syncthreads();
  }
}

extern "C" void kernel_launch(void* const* d_in, const int* in_sizes, int n_in,
                              void* d_out, int out_size, void* d_ws, size_t ws_size,
                              hipStream_t stream) {
  const float* X      = (const float*)d_in[0];
  const float* weight = (const float*)d_in[1];
  const float* M      = (const float*)d_in[2];
  const float* shift  = (const float*)d_in[3];
  float* out = (float*)d_out;
  float* ws  = (float*)d_ws;
  int B = in_sizes[0] / 4096;      // 4096 matrices of 64x64
  float invB = 1.f / (float)B;
  int G = B / 4;                   // 4 matrices per block

  hipLaunchKernelGGL(kzero,   dim3(OFF_BASE / 256), dim3(256), 0, stream, ws);
  hipLaunchKernelGGL(kprep,   dim3(1), dim3(256), 0, stream, weight, M, ws);
  hipLaunchKernelGGL(k1,      dim3(G), dim3(256), 0, stream, X, out, ws);
  hipLaunchKernelGGL(ksmall2, dim3(1), dim3(256), 0, stream, ws, invB);
  hipLaunchKernelGGL(k2,      dim3(G), dim3(256), 0, stream, out, ws);
  hipLaunchKernelGGL(ksmall3, dim3(1), dim3(256), 0, stream, ws, invB);
  hipLaunchKernelGGL(k3,      dim3(G), dim3(256), 0, stream, out, ws);
  hipLaunchKernelGGL(kscale,  dim3(1), dim3(64), 0, stream, ws, shift, invB);
  hipLaunchKernelGGL(k4,      dim3(G), dim3(256), 0, stream, out, ws);
}

// Round 8
// 11088.065 us; speedup vs baseline: 1.3286x; 1.3054x over previous
//
#include <hip/hip_runtime.h>
#include <math.h>

#define PITCH 72      // small-kernel LDS layout
#define NP 68         // batch LDS pitch: word(row r, col c) = 68r+c
#define SW_BATCH 12
#define SW_SMALL 10
#define NPART 32
#define EPS2_ROT 1e-12f   // (1e-6)^2 on d^2

// ---- workspace float-offsets ----
#define OFF_ACCG 0
#define OFF_ACCT (NPART*4096)
#define OFF_BASE (2*NPART*4096)
#define SL_MNH  (OFF_BASE + 0*4096)
#define SL_MH   (OFF_BASE + 1*4096)
#define SL_WH   (OFF_BASE + 2*4096)
#define SL_MU   SL_WH                 // WH dead after kprep; reused for k4's mu[B]
#define SL_P    (OFF_BASE + 3*4096)
#define SL_Q    (OFF_BASE + 4*4096)
#define SL_GH   (OFF_BASE + 5*4096)
#define SL_GNH  (OFF_BASE + 6*4096)
#define SL_MNH2 (OFF_BASE + 7*4096)
#define SL_WCH  (OFF_BASE + 8*4096)
#define OFF_VAR (OFF_BASE + 9*4096)
#define SL_SC   (OFF_BASE + 9*4096 + 1)
#define SL_R    (OFF_BASE + 10*4096)  // R = MNH2 * GH (non-symmetric)

struct __align__(16) F4 { float v[4]; };

// ======================================================================
// register-resident wave-synchronous one-sided Jacobi (1 wave : 1 matrix)
// lane l holds column l (= row l, symmetric) in own[64].
// XOR ordering: round m pairs lane l with l^m; both lanes compute bitwise-
// identical d. SINGLE-PASS: pv[64] fetched once, reused by the rotation.
// Needs ~150 live VGPRs -> only called from __launch_bounds__(64,1)
// kernels (budget 512) or the 1-block small kernels (spill there is cheap).
// ======================================================================
__device__ __forceinline__ void hestenes_reg(float (&own)[64], float& w2out, int sweeps) {
  const int lane = threadIdx.x & 63;
  float nrm = 0.f;
#pragma unroll
  for (int i = 0; i < 64; ++i) nrm = fmaf(own[i], own[i], nrm);

  for (int s = 0; s < sweeps; ++s) {
    bool any = false;
    for (int m = 1; m < 64; ++m) {
      float pv[64];
#pragma unroll
      for (int i = 0; i < 64; ++i) pv[i] = __shfl_xor(own[i], m);
      float d0 = 0.f, d1 = 0.f, d2 = 0.f, d3 = 0.f;
#pragma unroll
      for (int i = 0; i < 64; i += 4) {
        d0 = fmaf(own[i + 0], pv[i + 0], d0);
        d1 = fmaf(own[i + 1], pv[i + 1], d1);
        d2 = fmaf(own[i + 2], pv[i + 2], d2);
        d3 = fmaf(own[i + 3], pv[i + 3], d3);
      }
      float d = (d0 + d1) + (d2 + d3);
      float pn = __shfl_xor(nrm, m);
      if (d * d > EPS2_ROT * (nrm * pn)) {     // pair-uniform (bitwise-symmetric)
        any = true;
        bool lo = lane < (lane ^ m);
        float dpp = lo ? nrm : pn;
        float dqq = lo ? pn : nrm;
        float tau = (dqq - dpp) * (0.5f * __builtin_amdgcn_rcpf(d));
        float tt = __builtin_amdgcn_rcpf(fabsf(tau) +
                                         __builtin_amdgcn_sqrtf(fmaf(tau, tau, 1.f)));
        if (tau < 0.f) tt = -tt;
        float c = __builtin_amdgcn_rsqf(fmaf(tt, tt, 1.f));
        float s_ = tt * c;
        float sg = lo ? -s_ : s_;
#pragma unroll
        for (int i = 0; i < 64; ++i) own[i] = fmaf(sg, pv[i], c * own[i]);
        float td = tt * d;
        nrm += lo ? -td : td;
      }
    }
    if (!__any((int)any)) break;
  }
  float w = 0.f;
#pragma unroll
  for (int i = 0; i < 64; ++i) w = fmaf(own[i], own[i], w);
  w2out = w;
}

// ======================================================================
// dedicated eigensolve kernel: 64 threads = 1 wave per matrix, ZERO LDS,
// __launch_bounds__(64,1) -> VGPR budget 512 -> own+pv register-resident.
// Reads matrix rows from src, writes eigenrows (lambda_k * u_k^T) to buf.
// src may alias buf (in-place): each lane reads only its row up-front.
// ======================================================================
__global__ __launch_bounds__(64, 1) void keig(float* __restrict__ buf,
                                              const float* __restrict__ src) {
  const int l = threadIdx.x;
  const size_t b = blockIdx.x;
  const float* Sm = src + b * 4096 + (size_t)l * 64;
  float own[64];
#pragma unroll
  for (int j = 0; j < 16; ++j) {
    F4 r = *(const F4*)&Sm[4 * j];
    own[4 * j + 0] = r.v[0]; own[4 * j + 1] = r.v[1];
    own[4 * j + 2] = r.v[2]; own[4 * j + 3] = r.v[3];
  }
  float w2;
  hestenes_reg(own, w2, SW_BATCH);   // w2 recovered downstream as row-norm^2
  float* Dm = buf + b * 4096 + (size_t)l * 64;
#pragma unroll
  for (int j = 0; j < 16; ++j) {
    F4 o = {{own[4 * j], own[4 * j + 1], own[4 * j + 2], own[4 * j + 3]}};
    *(F4*)&Dm[4 * j] = o;
  }
}

// ======================================================================
// OLD infrastructure (PITCH 72) — 1-block small kernels
// ======================================================================
struct __align__(16) Smem {
  float S0[64*PITCH];
  float S1[64*PITCH];
  float w2[64];
  float wc[64];
  float red[256];
};

__device__ __forceinline__ void g2s(float* dst, const float* __restrict__ src) {
  int t = threadIdx.x;
#pragma unroll
  for (int i = 0; i < 4; ++i) {
    int e4 = t + (i << 8);
    F4 vv = *(const F4*)&src[e4 * 4];
    *(F4*)&dst[(e4 >> 4) * PITCH + (e4 & 15) * 4] = vv;
  }
  __syncthreads();
}
__device__ __forceinline__ void s2g(float* __restrict__ dst, const float* src) {
  int t = threadIdx.x;
#pragma unroll
  for (int i = 0; i < 4; ++i) {
    int e4 = t + (i << 8);
    F4 vv = *(const F4*)&src[(e4 >> 4) * PITCH + (e4 & 15) * 4];
    *(F4*)&dst[e4 * 4] = vv;
  }
  __syncthreads();
}

template<int MODE>   // 0: S0<-S1*S0 ; 1: S0<-S0*S1
__device__ void mmX(Smem& sm) {
  int t = threadIdx.x;
  int R0 = t >> 4;
  int J = (t & 15) * 4;
  float acc[4][4] = {};
  for (int kb = 0; kb < 64; kb += 4) {
    F4 a4[4], b4[4];
#pragma unroll
    for (int i = 0; i < 4; ++i) {
      const float* L = (MODE == 0) ? sm.S1 : sm.S0;
      a4[i] = *(const F4*)&L[(R0 + 16 * i) * PITCH + kb];
    }
#pragma unroll
    for (int kk = 0; kk < 4; ++kk) {
      const float* Rp = (MODE == 0) ? sm.S0 : sm.S1;
      b4[kk] = *(const F4*)&Rp[(kb + kk) * PITCH + J];
    }
#pragma unroll
    for (int i = 0; i < 4; ++i)
#pragma unroll
      for (int kk = 0; kk < 4; ++kk)
#pragma unroll
        for (int m = 0; m < 4; ++m)
          acc[i][m] = fmaf(a4[i].v[kk], b4[kk].v[m], acc[i][m]);
  }
  __syncthreads();
#pragma unroll
  for (int i = 0; i < 4; ++i) {
    F4 o;
#pragma unroll
    for (int m = 0; m < 4; ++m) o.v[m] = acc[i][m];
    *(F4*)&sm.S0[(R0 + 16 * i) * PITCH + J] = o;
  }
  __syncthreads();
}

__device__ void reconT(Smem& sm) {
  __syncthreads();
  int t = threadIdx.x;
  int R0 = t >> 4;
  int J = (t & 15) * 4;
  float acc[4][4] = {};
  for (int k = 0; k < 64; ++k) {
    float w = sm.wc[k];
    float a[4];
#pragma unroll
    for (int i = 0; i < 4; ++i) a[i] = w * sm.S0[k * PITCH + R0 + 16 * i];
    F4 b = *(const F4*)&sm.S0[k * PITCH + J];
#pragma unroll
    for (int i = 0; i < 4; ++i)
#pragma unroll
      for (int m = 0; m < 4; ++m) acc[i][m] = fmaf(a[i], b.v[m], acc[i][m]);
  }
#pragma unroll
  for (int i = 0; i < 4; ++i) {
    F4 o;
#pragma unroll
    for (int m = 0; m < 4; ++m) o.v[m] = acc[i][m];
    *(F4*)&sm.S1[(R0 + 16 * i) * PITCH + J] = o;
  }
  __syncthreads();
}

__device__ float frob2(Smem& sm) {
  int t = threadIdx.x;
  float s = 0.f;
#pragma unroll
  for (int i = 0; i < 4; ++i) {
    int e4 = t + (i << 8);
    F4 vv = *(const F4*)&sm.S0[(e4 >> 4) * PITCH + (e4 & 15) * 4];
#pragma unroll
    for (int m = 0; m < 4; ++m) s = fmaf(vv.v[m], vv.v[m], s);
  }
  sm.red[t] = s;
  __syncthreads();
  for (int o = 128; o; o >>= 1) { if (t < o) sm.red[t] += sm.red[t + o]; __syncthreads(); }
  float f = sm.red[0];
  __syncthreads();
  return f;
}

// wave-0 register Jacobi on the PITCH-72 tile (small kernels only)
__device__ void hestenes_small(Smem& sm, int sweeps) {
  const int t = threadIdx.x;
  if (t < 64) {
    float own[64];
#pragma unroll
    for (int i = 0; i < 64; ++i) own[i] = sm.S0[t * PITCH + i];
    float w2;
    hestenes_reg(own, w2, sweeps);
#pragma unroll
    for (int i = 0; i < 64; ++i) sm.S0[t * PITCH + i] = own[i];
    sm.w2[t] = w2;
  }
  __syncthreads();
}

// ======================================================================
// batch 256-thread infrastructure (pitch 68), 4 matrices per block
// ======================================================================
struct __align__(16) SmemK {      // 36.1 KB -> 4 blocks/CU
  float A[64*NP];
  float Bop[64*NP];
  float wc[64];
  float red[256];
};

__device__ __forceinline__ void g2s68(float* dst, const float* __restrict__ src) {
  int t = threadIdx.x;
#pragma unroll
  for (int i = 0; i < 4; ++i) {
    int e4 = t + (i << 8);
    F4 vv = *(const F4*)&src[e4 * 4];
    *(F4*)&dst[(e4 >> 4) * NP + (e4 & 15) * 4] = vv;
  }
  __syncthreads();
}
__device__ __forceinline__ void g2s68s(float* dst, const float* __restrict__ src, float sc) {
  int t = threadIdx.x;
#pragma unroll
  for (int i = 0; i < 4; ++i) {
    int e4 = t + (i << 8);
    F4 vv = *(const F4*)&src[e4 * 4];
#pragma unroll
    for (int m = 0; m < 4; ++m) vv.v[m] *= sc;
    *(F4*)&dst[(e4 >> 4) * NP + (e4 & 15) * 4] = vv;
  }
  __syncthreads();
}
__device__ __forceinline__ void s2g68(float* __restrict__ dst, const float* src) {
  int t = threadIdx.x;
#pragma unroll
  for (int i = 0; i < 4; ++i) {
    int e4 = t + (i << 8);
    F4 vv = *(const F4*)&src[(e4 >> 4) * NP + (e4 & 15) * 4];
    *(F4*)&dst[e4 * 4] = vv;
  }
  __syncthreads();
}

// row-norm^2 of LDS row t (recovers lambda^2 from eigenrows; no w2 storage)
__device__ __forceinline__ float rown2(const float* A, int t) {
  float s = 0.f;
#pragma unroll
  for (int j = 0; j < 64; ++j) { float v = A[t * NP + j]; s = fmaf(v, v, s); }
  return fmaxf(s, 1e-12f);
}

// MODE 0: A <- Bo*A ; 1: A <- A*Bo ; 2: A <- A*Bo^T   (in-place on A)
template<int MODE>
__device__ void mm68(float* A, const float* Bo) {
  int t = threadIdx.x;
  int R0 = t >> 4;
  if (MODE == 2) {
    int J0 = t & 15;
    float acc[4][4] = {};
    for (int kb = 0; kb < 64; kb += 4) {
      F4 a4[4];
#pragma unroll
      for (int i = 0; i < 4; ++i) a4[i] = *(const F4*)&A[(R0 + 16 * i) * NP + kb];
#pragma unroll
      for (int kk = 0; kk < 4; ++kk) {
        float b[4];
#pragma unroll
        for (int m = 0; m < 4; ++m) b[m] = Bo[(J0 + 16 * m) * NP + kb + kk];
#pragma unroll
        for (int i = 0; i < 4; ++i)
#pragma unroll
          for (int m = 0; m < 4; ++m) acc[i][m] = fmaf(a4[i].v[kk], b[m], acc[i][m]);
      }
    }
    __syncthreads();
#pragma unroll
    for (int i = 0; i < 4; ++i)
#pragma unroll
      for (int m = 0; m < 4; ++m)
        A[(R0 + 16 * i) * NP + J0 + 16 * m] = acc[i][m];
    __syncthreads();
  } else {
    int J = (t & 15) * 4;
    float acc[4][4] = {};
    for (int kb = 0; kb < 64; kb += 4) {
      F4 a4[4], b4[4];
#pragma unroll
      for (int i = 0; i < 4; ++i) {
        const float* L = (MODE == 0) ? Bo : A;
        a4[i] = *(const F4*)&L[(R0 + 16 * i) * NP + kb];
      }
#pragma unroll
      for (int kk = 0; kk < 4; ++kk) {
        const float* Rp = (MODE == 0) ? A : Bo;
        b4[kk] = *(const F4*)&Rp[(kb + kk) * NP + J];
      }
#pragma unroll
      for (int i = 0; i < 4; ++i)
#pragma unroll
        for (int kk = 0; kk < 4; ++kk)
#pragma unroll
          for (int m = 0; m < 4; ++m)
            acc[i][m] = fmaf(a4[i].v[kk], b4[kk].v[m], acc[i][m]);
    }
    __syncthreads();
#pragma unroll
    for (int i = 0; i < 4; ++i) {
      F4 o;
#pragma unroll
      for (int m = 0; m < 4; ++m) o.v[m] = acc[i][m];
      *(F4*)&A[(R0 + 16 * i) * NP + J] = o;
    }
    __syncthreads();
  }
}

__device__ float frob68(const float* A, float* red) {
  int t = threadIdx.x;
  float s = 0.f;
#pragma unroll
  for (int i = 0; i < 4; ++i) {
    int e4 = t + (i << 8);
    F4 vv = *(const F4*)&A[(e4 >> 4) * NP + (e4 & 15) * 4];
#pragma unroll
    for (int m = 0; m < 4; ++m) s = fmaf(vv.v[m], vv.v[m], s);
  }
  red[t] = s;
  __syncthreads();
  for (int o = 128; o; o >>= 1) { if (t < o) red[t] += red[t + o]; __syncthreads(); }
  float f = red[0];
  __syncthreads();
  return f;
}

// Z*Z -> global (row-major 64x64), reads Z (pitch 68)
__device__ void msq_store(const float* Z, float* __restrict__ gout) {
  int t = threadIdx.x;
  int R0 = t >> 4;
  int J = (t & 15) * 4;
  float acc[4][4] = {};
  for (int kb = 0; kb < 64; kb += 4) {
    F4 a4[4], b4[4];
#pragma unroll
    for (int i = 0; i < 4; ++i) a4[i] = *(const F4*)&Z[(R0 + 16 * i) * NP + kb];
#pragma unroll
    for (int kk = 0; kk < 4; ++kk) b4[kk] = *(const F4*)&Z[(kb + kk) * NP + J];
#pragma unroll
    for (int i = 0; i < 4; ++i)
#pragma unroll
      for (int kk = 0; kk < 4; ++kk)
#pragma unroll
        for (int m = 0; m < 4; ++m)
          acc[i][m] = fmaf(a4[i].v[kk], b4[kk].v[m], acc[i][m]);
  }
#pragma unroll
  for (int i = 0; i < 4; ++i) {
    F4 o;
#pragma unroll
    for (int m = 0; m < 4; ++m) o.v[m] = acc[i][m];
    *(F4*)&gout[(R0 + 16 * i) * 64 + J] = o;
  }
}

// ============================ kernels ============================

__global__ __launch_bounds__(256) void kzero(float* ws) {
  int i = blockIdx.x * 256 + threadIdx.x;
  if (i < OFF_BASE) ws[i] = 0.f;
  if (i == 0) ws[OFF_VAR] = 0.f;
}

// Mnh/Mh/Wh -> P = Wc^{-1/2} Wh, Q = Mh Wc^{1/2}
__global__ __launch_bounds__(256, 1) void kprep(const float* __restrict__ weight,
                                                const float* __restrict__ M,
                                                float* ws) {
  __shared__ Smem sm;
  int t = threadIdx.x;
  g2s(sm.S0, M);
  hestenes_small(sm, SW_SMALL);
  if (t < 64) sm.wc[t] = powf(fmaxf(sm.w2[t], 1e-12f), -1.25f);
  reconT(sm); s2g(ws + SL_MNH, sm.S1);
  if (t < 64) sm.wc[t] = powf(fmaxf(sm.w2[t], 1e-12f), -0.75f);
  reconT(sm); s2g(ws + SL_MH, sm.S1);

  g2s(sm.S0, weight);
  hestenes_small(sm, SW_SMALL);
  if (t < 64) sm.wc[t] = powf(fmaxf(sm.w2[t], 1e-12f), -0.75f);
  reconT(sm); s2g(ws + SL_WH, sm.S1);

  g2s(sm.S0, ws + SL_MNH);
  mmX<1>(sm);
  g2s(sm.S1, ws + SL_MNH);
  mmX<1>(sm);
  hestenes_small(sm, SW_SMALL);
  if (t < 64) sm.wc[t] = powf(fmaxf(sm.w2[t], 1e-12f), -0.75f);
  reconT(sm); s2g(ws + SL_WCH, sm.S1);
  if (t < 64) sm.wc[t] = powf(fmaxf(sm.w2[t], 1e-12f), -1.25f);
  reconT(sm);
  g2s(sm.S0, ws + SL_WH);
  mmX<0>(sm);
  s2g(ws + SL_P, sm.S0);
  g2s(sm.S0, ws + SL_WCH);
  g2s(sm.S1, ws + SL_MH);
  mmX<0>(sm);
  s2g(ws + SL_Q, sm.S0);
}

// E1 + Mnh -> Xc (in place in buf) ; accumulate sum(Xc)
__global__ __launch_bounds__(256, 4) void k1b(float* __restrict__ buf, float* ws) {
  __shared__ SmemK sm;
  int t = threadIdx.x;
  size_t b = blockIdx.x;
  g2s68(sm.Bop, ws + SL_MNH);
  int R0 = t >> 4, J = (t & 15) * 4;
  for (int m = 0; m < 4; ++m) {
    size_t bm = b * 4 + m;
    g2s68(sm.A, buf + bm * 4096);                       // eigenrows e_k
    if (t < 64) sm.wc[t] = powf(rown2(sm.A, t), -0.75f); // sqrt: lam^{1/2-2}
    __syncthreads();
    mm68<1>(sm.A, sm.Bop);                              // rows = (Mnh e_k)^T
    float acc[4][4] = {};
    for (int k = 0; k < 64; ++k) {
      float wck = sm.wc[k];
      float a[4];
#pragma unroll
      for (int i = 0; i < 4; ++i) a[i] = wck * sm.A[k * NP + R0 + 16 * i];
      F4 bb = *(const F4*)&sm.A[k * NP + J];
#pragma unroll
      for (int i = 0; i < 4; ++i)
#pragma unroll
        for (int mc = 0; mc < 4; ++mc) acc[i][mc] = fmaf(a[i], bb.v[mc], acc[i][mc]);
    }
    float* Xc = buf + bm * 4096;
    float* accp = ws + OFF_ACCG + (size_t)(bm & (NPART - 1)) * 4096;
#pragma unroll
    for (int i = 0; i < 4; ++i) {
      F4 o;
#pragma unroll
      for (int mc = 0; mc < 4; ++mc) o.v[mc] = acc[i][mc];
      int base = (R0 + 16 * i) * 64 + J;
      *(F4*)&Xc[base] = o;
#pragma unroll
      for (int mc = 0; mc < 4; ++mc) atomicAdd(accp + base + mc, o.v[mc]);
    }
    __syncthreads();
  }
}

// G0 = mean(Xc); eig -> G0h, G0nh
__global__ __launch_bounds__(256, 1) void ksmall2(float* ws, float invB) {
  __shared__ Smem sm;
  int t = threadIdx.x;
#pragma unroll
  for (int i = 0; i < 4; ++i) {
    int e4 = t + (i << 8);
    F4 sum = {{0.f, 0.f, 0.f, 0.f}};
    for (int p = 0; p < NPART; ++p) {
      F4 vv = *(const F4*)&ws[OFF_ACCG + p * 4096 + e4 * 4];
#pragma unroll
      for (int m = 0; m < 4; ++m) sum.v[m] += vv.v[m];
    }
#pragma unroll
    for (int m = 0; m < 4; ++m) sum.v[m] *= invB;
    *(F4*)&sm.S0[(e4 >> 4) * PITCH + (e4 & 15) * 4] = sum;
  }
  __syncthreads();
  hestenes_small(sm, SW_SMALL);
  if (t < 64) sm.wc[t] = powf(fmaxf(sm.w2[t], 1e-12f), -0.75f);
  reconT(sm); s2g(ws + SL_GH, sm.S1);
  if (t < 64) sm.wc[t] = powf(fmaxf(sm.w2[t], 1e-12f), -1.25f);
  reconT(sm); s2g(ws + SL_GNH, sm.S1);
}

// Xc -> A = Gnh Xc Gnh (in place)
__global__ __launch_bounds__(256, 4) void kcongr(float* __restrict__ buf, float* ws) {
  __shared__ SmemK sm;
  size_t b = blockIdx.x;
  g2s68(sm.Bop, ws + SL_GNH);
  for (int m = 0; m < 4; ++m) {
    size_t bm = b * 4 + m;
    g2s68(sm.A, buf + bm * 4096);
    mm68<1>(sm.A, sm.Bop);
    mm68<0>(sm.A, sm.Bop);
    s2g68(buf + bm * 4096, sm.A);
  }
}

// E2 -> accumulate sum log via recon with log-weights
__global__ __launch_bounds__(256, 4) void k2b(const float* __restrict__ buf, float* ws) {
  __shared__ SmemK sm;
  int t = threadIdx.x;
  size_t b = blockIdx.x;
  int R0 = t >> 4, J = (t & 15) * 4;
  for (int m = 0; m < 4; ++m) {
    size_t bm = b * 4 + m;
    g2s68(sm.A, buf + bm * 4096);
    if (t < 64) {
      float s2 = rown2(sm.A, t);
      sm.wc[t] = 0.5f * logf(s2) / s2;       // log(lam)/lam^2
    }
    __syncthreads();
    float acc[4][4] = {};
    for (int k = 0; k < 64; ++k) {
      float wck = sm.wc[k];
      float a[4];
#pragma unroll
      for (int i = 0; i < 4; ++i) a[i] = wck * sm.A[k * NP + R0 + 16 * i];
      F4 bb = *(const F4*)&sm.A[k * NP + J];
#pragma unroll
      for (int i = 0; i < 4; ++i)
#pragma unroll
        for (int mc = 0; mc < 4; ++mc) acc[i][mc] = fmaf(a[i], bb.v[mc], acc[i][mc]);
    }
    float* accp = ws + OFF_ACCT + (size_t)(bm & (NPART - 1)) * 4096;
#pragma unroll
    for (int i = 0; i < 4; ++i) {
      int base = (R0 + 16 * i) * 64 + J;
#pragma unroll
      for (int mc = 0; mc < 4; ++mc) atomicAdd(accp + base + mc, acc[i][mc]);
    }
    __syncthreads();
  }
}

// Tbar -> mean_G -> mnh ; also R = mnh * G0h
__global__ __launch_bounds__(256, 1) void ksmall3(float* ws, float invB) {
  __shared__ Smem sm;
  int t = threadIdx.x;
#pragma unroll
  for (int i = 0; i < 4; ++i) {
    int e4 = t + (i << 8);
    F4 sum = {{0.f, 0.f, 0.f, 0.f}};
    for (int p = 0; p < NPART; ++p) {
      F4 vv = *(const F4*)&ws[OFF_ACCT + p * 4096 + e4 * 4];
#pragma unroll
      for (int m = 0; m < 4; ++m) sum.v[m] += vv.v[m];
    }
#pragma unroll
    for (int m = 0; m < 4; ++m) sum.v[m] *= invB;
    *(F4*)&sm.S0[(e4 >> 4) * PITCH + (e4 & 15) * 4] = sum;
  }
  __syncthreads();
  float mu = sqrtf(frob2(sm)) + 1e-3f;        // exp of indefinite: shift to SPD
  if (t < 64) sm.S0[t * PITCH + t] += mu;
  __syncthreads();
  hestenes_small(sm, SW_SMALL);
  if (t < 64) {
    float s2 = fmaxf(sm.w2[t], 1e-12f);
    sm.wc[t] = expf(sqrtf(s2) - mu) / s2;
  }
  reconT(sm);
  g2s(sm.S0, ws + SL_GH);
  mmX<1>(sm);
  g2s(sm.S1, ws + SL_GH);
  mmX<1>(sm);                                  // mean_G
  hestenes_small(sm, SW_SMALL);
  if (t < 64) sm.wc[t] = powf(fmaxf(sm.w2[t], 1e-12f), -1.25f);
  reconT(sm); s2g(ws + SL_MNH2, sm.S1);
  // R = MNH2 * GH  (so that mnh Xc mnh = R A R^T with A = Gnh Xc Gnh)
  g2s(sm.S0, ws + SL_MNH2);
  g2s(sm.S1, ws + SL_GH);
  mmX<1>(sm);
  s2g(ws + SL_R, sm.S0);
}

// E2 + R -> B = R A R^T (in place): F = E2*R^T, B = sum lam^{-1} f f^T
__global__ __launch_bounds__(256, 4) void k3pre(float* __restrict__ buf, float* ws) {
  __shared__ SmemK sm;
  int t = threadIdx.x;
  size_t b = blockIdx.x;
  g2s68(sm.Bop, ws + SL_R);
  int R0 = t >> 4, J = (t & 15) * 4;
  for (int m = 0; m < 4; ++m) {
    size_t bm = b * 4 + m;
    g2s68(sm.A, buf + bm * 4096);
    if (t < 64) sm.wc[t] = powf(rown2(sm.A, t), -0.5f);   // 1/lam
    __syncthreads();
    mm68<2>(sm.A, sm.Bop);                                 // F = E2 * R^T
    float acc[4][4] = {};
    for (int k = 0; k < 64; ++k) {
      float wck = sm.wc[k];
      float a[4];
#pragma unroll
      for (int i = 0; i < 4; ++i) a[i] = wck * sm.A[k * NP + R0 + 16 * i];
      F4 bb = *(const F4*)&sm.A[k * NP + J];
#pragma unroll
      for (int i = 0; i < 4; ++i)
#pragma unroll
        for (int mc = 0; mc < 4; ++mc) acc[i][mc] = fmaf(a[i], bb.v[mc], acc[i][mc]);
    }
    float* Bg = buf + bm * 4096;
#pragma unroll
    for (int i = 0; i < 4; ++i) {
      F4 o;
#pragma unroll
      for (int mc = 0; mc < 4; ++mc) o.v[mc] = acc[i][mc];
      *(F4*)&Bg[(R0 + 16 * i) * 64 + J] = o;
    }
    __syncthreads();
  }
}

// E3 -> T (in place) + ||T||_F^2 accumulation
__global__ __launch_bounds__(256, 4) void k3b(float* __restrict__ buf, float* ws) {
  __shared__ SmemK sm;
  int t = threadIdx.x;
  size_t b = blockIdx.x;
  int R0 = t >> 4, J = (t & 15) * 4;
  for (int m = 0; m < 4; ++m) {
    size_t bm = b * 4 + m;
    g2s68(sm.A, buf + bm * 4096);
    if (t < 64) {
      float s2 = rown2(sm.A, t);
      sm.wc[t] = 0.5f * logf(s2) / s2;
    }
    __syncthreads();
    float acc[4][4] = {};
    for (int k = 0; k < 64; ++k) {
      float wck = sm.wc[k];
      float a[4];
#pragma unroll
      for (int i = 0; i < 4; ++i) a[i] = wck * sm.A[k * NP + R0 + 16 * i];
      F4 bb = *(const F4*)&sm.A[k * NP + J];
#pragma unroll
      for (int i = 0; i < 4; ++i)
#pragma unroll
        for (int mc = 0; mc < 4; ++mc) acc[i][mc] = fmaf(a[i], bb.v[mc], acc[i][mc]);
    }
    float* Tg = buf + bm * 4096;
    float ssq = 0.f;
#pragma unroll
    for (int i = 0; i < 4; ++i) {
      F4 o;
#pragma unroll
      for (int mc = 0; mc < 4; ++mc) o.v[mc] = acc[i][mc];
      int base = (R0 + 16 * i) * 64 + J;
      *(F4*)&Tg[base] = o;
#pragma unroll
      for (int mc = 0; mc < 4; ++mc) ssq = fmaf(o.v[mc], o.v[mc], ssq);
    }
    sm.red[t] = ssq;
    __syncthreads();
    for (int o = 128; o; o >>= 1) { if (t < o) sm.red[t] += sm.red[t + o]; __syncthreads(); }
    if (t == 0) atomicAdd(ws + OFF_VAR, sm.red[0]);
    __syncthreads();
  }
}

__global__ void kscale(float* ws, const float* __restrict__ shift, float invB) {
  if (threadIdx.x == 0 && blockIdx.x == 0) {
    float var = ws[OFF_VAR] * invB;
    ws[SL_SC] = shift[0] / sqrtf(var + 1e-5f);
  }
}

// T -> S = P (sc T) P^T + mu I (in place), store mu
__global__ __launch_bounds__(256, 4) void k4pre(float* __restrict__ buf, float* ws) {
  __shared__ SmemK sm;
  int t = threadIdx.x;
  size_t b = blockIdx.x;
  float sc = ws[SL_SC];
  g2s68(sm.Bop, ws + SL_P);
  for (int m = 0; m < 4; ++m) {
    size_t bm = b * 4 + m;
    g2s68s(sm.A, buf + bm * 4096, sc);
    mm68<0>(sm.A, sm.Bop);                 // P*(scT)
    mm68<2>(sm.A, sm.Bop);                 // *P^T  (symmetric indefinite)
    float f = frob68(sm.A, sm.red);
    float mu = sqrtf(f) + 1e-3f;
    if (t == 0) ws[SL_MU + bm] = mu;
    float* Sg = buf + bm * 4096;
#pragma unroll
    for (int i = 0; i < 4; ++i) {
      int e4 = t + (i << 8);
      int row = e4 >> 4;
      F4 v = *(const F4*)&sm.A[row * NP + (e4 & 15) * 4];
#pragma unroll
      for (int mc = 0; mc < 4; ++mc)
        if ((e4 & 15) * 4 + mc == row) v.v[mc] += mu;
      *(F4*)&Sg[e4 * 4] = v;
    }
    __syncthreads();
  }
}

// E4 + Q -> Y = (Q E Q^T)^2 (in place)
__global__ __launch_bounds__(256, 4) void k4b(float* __restrict__ buf, float* ws) {
  __shared__ SmemK sm;
  int t = threadIdx.x;
  size_t b = blockIdx.x;
  int R0 = t >> 4, J = (t & 15) * 4;
  for (int m = 0; m < 4; ++m) {
    size_t bm = b * 4 + m;
    g2s68(sm.A, buf + bm * 4096);              // E4
    float mu = ws[SL_MU + bm];
    if (t < 64) {
      float s2 = rown2(sm.A, t);
      sm.wc[t] = expf(sqrtf(s2) - mu) / s2;
    }
    __syncthreads();
    g2s68(sm.Bop, ws + SL_Q);                  // reload Q (Bop reused as Z below)
    mm68<2>(sm.A, sm.Bop);                     // rows = lam (Q u)^T
    float acc[4][4] = {};
    for (int k = 0; k < 64; ++k) {
      float wck = sm.wc[k];
      float a[4];
#pragma unroll
      for (int i = 0; i < 4; ++i) a[i] = wck * sm.A[k * NP + R0 + 16 * i];
      F4 bb = *(const F4*)&sm.A[k * NP + J];
#pragma unroll
      for (int i = 0; i < 4; ++i)
#pragma unroll
        for (int mc = 0; mc < 4; ++mc) acc[i][mc] = fmaf(a[i], bb.v[mc], acc[i][mc]);
    }
#pragma unroll
    for (int i = 0; i < 4; ++i) {
      F4 o;
#pragma unroll
      for (int mc = 0; mc < 4; ++mc) o.v[mc] = acc[i][mc];
      *(F4*)&sm.Bop[(R0 + 16 * i) * NP + J] = o;   // Z = Q E Q^T
    }
    __syncthreads();
    msq_store(sm.Bop, buf + bm * 4096);            // Y = Z*Z
    __syncthreads();
  }
}

extern "C" void kernel_launch(void* const* d_in, const int* in_sizes, int n_in,
                              void* d_out, int out_size, void* d_ws, size_t ws_size,
                              hipStream_t stream) {
  const float* X      = (const float*)d_in[0];
  const float* weight = (const float*)d_in[1];
  const float* M      = (const float*)d_in[2];
  const float* shift  = (const float*)d_in[3];
  float* out = (float*)d_out;
  float* ws  = (float*)d_ws;
  int B = in_sizes[0] / 4096;      // 4096 matrices of 64x64
  float invB = 1.f / (float)B;
  int G = B / 4;

  hipLaunchKernelGGL(kzero,   dim3(OFF_BASE / 256), dim3(256), 0, stream, ws);
  hipLaunchKernelGGL(kprep,   dim3(1), dim3(256), 0, stream, weight, M, ws);
  hipLaunchKernelGGL(keig,    dim3(B), dim3(64), 0, stream, out, X);     // E1
  hipLaunchKernelGGL(k1b,     dim3(G), dim3(256), 0, stream, out, ws);   // Xc + sum
  hipLaunchKernelGGL(ksmall2, dim3(1), dim3(256), 0, stream, ws, invB);
  hipLaunchKernelGGL(kcongr,  dim3(G), dim3(256), 0, stream, out, ws);   // A
  hipLaunchKernelGGL(keig,    dim3(B), dim3(64), 0, stream, out, out);   // E2
  hipLaunchKernelGGL(k2b,     dim3(G), dim3(256), 0, stream, out, ws);   // sum log
  hipLaunchKernelGGL(ksmall3, dim3(1), dim3(256), 0, stream, ws, invB);
  hipLaunchKernelGGL(k3pre,   dim3(G), dim3(256), 0, stream, out, ws);   // B
  hipLaunchKernelGGL(keig,    dim3(B), dim3(64), 0, stream, out, out);   // E3
  hipLaunchKernelGGL(k3b,     dim3(G), dim3(256), 0, stream, out, ws);   // T + var
  hipLaunchKernelGGL(kscale,  dim3(1), dim3(64), 0, stream, ws, shift, invB);
  hipLaunchKernelGGL(k4pre,   dim3(G), dim3(256), 0, stream, out, ws);   // S + mu I
  hipLaunchKernelGGL(keig,    dim3(B), dim3(64), 0, stream, out, out);   // E4
  hipLaunchKernelGGL(k4b,     dim3(G), dim3(256), 0, stream, out, ws);   // Y
}